// Round 1
// baseline (410.769 us; speedup 1.0000x reference)
//
#include <hip/hip_runtime.h>
#include <hip/hip_bf16.h>
#include <math.h>

#define NN 50000
#define FIN 48
#define HC 64   // 8 heads x 8 ch
#define NHEAD 8
#define NCH 8
#define NCLS 2
#define NEG 0.2f

// ---------------- CSR build ----------------

__global__ void k_fill(int* deg, int* cursor, int n) {
    int i = blockIdx.x * blockDim.x + threadIdx.x;
    if (i < n) { deg[i] = 1; cursor[i] = 0; }   // 1 = self-loop
}

__global__ void k_count(const int* ei, int* deg, int e) {
    int i = blockIdx.x * blockDim.x + threadIdx.x;
    if (i < e) atomicAdd(&deg[ei[e + i]], 1);   // row 1 = dst
}

#define SCAN_T 256
#define SCAN_E 1024

__global__ void k_scan1(const int* deg, int* bsum, int n) {
    __shared__ int lds[SCAN_T];
    int t = threadIdx.x;
    int base = blockIdx.x * SCAN_E + t * 4;
    int s = 0;
    #pragma unroll
    for (int k = 0; k < 4; ++k) { int idx = base + k; if (idx < n) s += deg[idx]; }
    lds[t] = s;
    __syncthreads();
    for (int off = SCAN_T / 2; off > 0; off >>= 1) {
        if (t < off) lds[t] += lds[t + off];
        __syncthreads();
    }
    if (t == 0) bsum[blockIdx.x] = lds[0];
}

__global__ void k_scan2(int* bsum, int nb) {
    if (threadIdx.x == 0 && blockIdx.x == 0) {
        int acc = 0;
        for (int i = 0; i < nb; ++i) { int v = bsum[i]; bsum[i] = acc; acc += v; }
    }
}

__global__ void k_scan3(const int* deg, const int* bsum, int* rowptr, int n) {
    __shared__ int lds[SCAN_T];
    int t = threadIdx.x;
    int base = blockIdx.x * SCAN_E + t * 4;
    int v[4]; int s = 0;
    #pragma unroll
    for (int k = 0; k < 4; ++k) { int idx = base + k; v[k] = (idx < n) ? deg[idx] : 0; s += v[k]; }
    lds[t] = s;
    __syncthreads();
    // Hillis-Steele inclusive scan (read -> sync -> write -> sync)
    for (int off = 1; off < SCAN_T; off <<= 1) {
        int y = (t >= off) ? lds[t - off] : 0;
        __syncthreads();
        lds[t] += y;
        __syncthreads();
    }
    int excl = lds[t] - s + bsum[blockIdx.x];
    #pragma unroll
    for (int k = 0; k < 4; ++k) {
        int idx = base + k;
        if (idx < n) rowptr[idx] = excl;
        excl += v[k];
    }
}

__global__ void k_scatter(const int* ei, const int* rowptr, int* cursor, int* csr,
                          int e, int n) {
    int i = blockIdx.x * blockDim.x + threadIdx.x;
    int tot = e + n;
    if (i >= tot) return;
    int s, d;
    if (i < e) { s = ei[i]; d = ei[e + i]; }
    else       { s = i - e; d = i - e; }       // self-loop
    int pos = atomicAdd(&cursor[d], 1);
    csr[rowptr[d] + pos] = s;
}

// ---------------- Layer 1: h1 = x @ W1 ; e_src/e_dst ----------------

__global__ void k_h1(const float* __restrict__ x, const float* __restrict__ W1,
                     const float* __restrict__ as1, const float* __restrict__ ad1,
                     float* __restrict__ h1, float* __restrict__ es1,
                     float* __restrict__ ed1, int n) {
    __shared__ float Wl[FIN * HC];
    __shared__ float xs[4][FIN];
    __shared__ float hr[4][HC];
    int tid = threadIdx.x;
    for (int i = tid; i < FIN * HC; i += 256) Wl[i] = W1[i];
    int nb = blockIdx.x * 4;
    for (int i = tid; i < 4 * FIN; i += 256) {
        int nl = i / FIN, k = i % FIN;
        int nd = nb + nl;
        xs[nl][k] = (nd < n) ? x[nd * FIN + k] : 0.f;
    }
    __syncthreads();
    int nl = tid >> 6, j = tid & 63;
    float acc = 0.f;
    #pragma unroll
    for (int k = 0; k < FIN; ++k) acc += xs[nl][k] * Wl[k * HC + j];
    int nd = nb + nl;
    if (nd < n) h1[nd * HC + j] = acc;
    hr[nl][j] = acc;
    __syncthreads();
    if (j < 16 && nd < n) {
        int hh = j & 7;
        const float* av = (j < 8) ? as1 : ad1;
        float ev = 0.f;
        #pragma unroll
        for (int c = 0; c < NCH; ++c) ev += hr[nl][hh * NCH + c] * av[hh * NCH + c];
        if (j < 8) es1[nd * NHEAD + hh] = ev;
        else       ed1[nd * NHEAD + hh] = ev;
    }
}

// ---------------- Layer 1 aggregation: wave per dst node, online softmax ----------------

__global__ void k_agg1(const float* __restrict__ h1, const float* __restrict__ es1,
                       const float* __restrict__ ed1, const int* __restrict__ rowptr,
                       const int* __restrict__ deg, const int* __restrict__ csr,
                       const float* __restrict__ b1, float* __restrict__ o1elu, int n) {
    int wid = (blockIdx.x * blockDim.x + threadIdx.x) >> 6;
    if (wid >= n) return;
    int lane = threadIdx.x & 63;
    int h = lane >> 3;
    int start = rowptr[wid];
    int cnt = deg[wid];
    float edv = ed1[wid * NHEAD + h];
    float m = -3.0e38f, sumw = 0.f, acc = 0.f;
    for (int i = 0; i < cnt; ++i) {
        int s = csr[start + i];
        float val = es1[s * NHEAD + h] + edv;
        val = val > 0.f ? val : NEG * val;
        float hv = h1[s * HC + lane];
        float nm = fmaxf(m, val);
        float sc = __expf(m - nm);
        float w  = __expf(val - nm);
        sumw = sumw * sc + w;
        acc  = acc  * sc + w * hv;
        m = nm;
    }
    float out = acc / sumw + b1[lane];
    o1elu[wid * HC + lane] = out > 0.f ? out : expm1f(out);   // fused bias + ELU
}

// ---------------- Layer 2: h2 = o1elu @ W2 ; e_src2/e_dst2 ----------------

__global__ void k_h2(const float* __restrict__ o1elu, const float* __restrict__ W2,
                     const float* __restrict__ as2, const float* __restrict__ ad2,
                     float* __restrict__ h2, float* __restrict__ es2,
                     float* __restrict__ ed2, int n) {
    int wid = (blockIdx.x * blockDim.x + threadIdx.x) >> 6;
    if (wid >= n) return;
    int lane = threadIdx.x & 63;
    float v = o1elu[wid * HC + lane];
    float p0 = v * W2[lane * NCLS + 0];
    float p1 = v * W2[lane * NCLS + 1];
    #pragma unroll
    for (int off = 32; off > 0; off >>= 1) {
        p0 += __shfl_xor(p0, off, 64);
        p1 += __shfl_xor(p1, off, 64);
    }
    if (lane == 0) {
        h2[wid * NCLS + 0] = p0;
        h2[wid * NCLS + 1] = p1;
        es2[wid] = p0 * as2[0] + p1 * as2[1];
        ed2[wid] = p0 * ad2[0] + p1 * ad2[1];
    }
}

// ---------------- Layer 2 aggregation + bias + log_softmax: thread per node ----------------

__global__ void k_agg2(const float* __restrict__ h2, const float* __restrict__ es2,
                       const float* __restrict__ ed2, const int* __restrict__ rowptr,
                       const int* __restrict__ deg, const int* __restrict__ csr,
                       const float* __restrict__ b2, float* __restrict__ out, int n) {
    int nd = blockIdx.x * blockDim.x + threadIdx.x;
    if (nd >= n) return;
    int start = rowptr[nd];
    int cnt = deg[nd];
    float edv = ed2[nd];
    float m = -3.0e38f, sw = 0.f, a0 = 0.f, a1 = 0.f;
    for (int i = 0; i < cnt; ++i) {
        int s = csr[start + i];
        float val = es2[s] + edv;
        val = val > 0.f ? val : NEG * val;
        float nm = fmaxf(m, val);
        float sc = __expf(m - nm);
        float w  = __expf(val - nm);
        sw = sw * sc + w;
        a0 = a0 * sc + w * h2[s * NCLS + 0];
        a1 = a1 * sc + w * h2[s * NCLS + 1];
        m = nm;
    }
    float z0 = a0 / sw + b2[0];
    float z1 = a1 / sw + b2[1];
    float mz = fmaxf(z0, z1);
    float lse = mz + logf(__expf(z0 - mz) + __expf(z1 - mz));
    out[nd * NCLS + 0] = z0 - lse;
    out[nd * NCLS + 1] = z1 - lse;
}

// ---------------- launch ----------------

extern "C" void kernel_launch(void* const* d_in, const int* in_sizes, int n_in,
                              void* d_out, int out_size, void* d_ws, size_t ws_size,
                              hipStream_t stream) {
    const float* x   = (const float*)d_in[0];
    const int*   ei  = (const int*)d_in[1];
    const float* W1  = (const float*)d_in[2];
    const float* as1 = (const float*)d_in[3];
    const float* ad1 = (const float*)d_in[4];
    const float* b1  = (const float*)d_in[5];
    const float* W2  = (const float*)d_in[6];
    const float* as2 = (const float*)d_in[7];
    const float* ad2 = (const float*)d_in[8];
    const float* b2  = (const float*)d_in[9];
    float* out = (float*)d_out;

    const int n = in_sizes[0] / FIN;     // 50000
    const int e = in_sizes[1] / 2;       // 1600000
    const int ea = e + n;

    char* ws = (char*)d_ws;
    size_t off = 0;
    auto alloc = [&](size_t bytes) -> void* {
        void* p = ws + off;
        off += (bytes + 255) & ~(size_t)255;
        return p;
    };
    float* h1    = (float*)alloc((size_t)n * HC * 4);
    float* o1elu = (float*)alloc((size_t)n * HC * 4);
    float* es1   = (float*)alloc((size_t)n * NHEAD * 4);
    float* ed1   = (float*)alloc((size_t)n * NHEAD * 4);
    float* h2    = (float*)alloc((size_t)n * NCLS * 4);
    float* es2   = (float*)alloc((size_t)n * 4);
    float* ed2   = (float*)alloc((size_t)n * 4);
    int* deg     = (int*)alloc((size_t)n * 4);
    int* rowptr  = (int*)alloc((size_t)n * 4);
    int* cursor  = (int*)alloc((size_t)n * 4);
    int* bsum    = (int*)alloc(256 * 4);
    int* csr     = (int*)alloc((size_t)ea * 4);

    const int nb_scan = (n + SCAN_E - 1) / SCAN_E;   // 49

    // CSR build
    k_fill<<<(n + 255) / 256, 256, 0, stream>>>(deg, cursor, n);
    k_count<<<(e + 255) / 256, 256, 0, stream>>>(ei, deg, e);
    k_scan1<<<nb_scan, SCAN_T, 0, stream>>>(deg, bsum, n);
    k_scan2<<<1, 64, 0, stream>>>(bsum, nb_scan);
    k_scan3<<<nb_scan, SCAN_T, 0, stream>>>(deg, bsum, rowptr, n);
    k_scatter<<<(ea + 255) / 256, 256, 0, stream>>>(ei, rowptr, cursor, csr, e, n);

    // Layer 1
    k_h1<<<(n + 3) / 4, 256, 0, stream>>>(x, W1, as1, ad1, h1, es1, ed1, n);
    k_agg1<<<(n * 64 + 255) / 256, 256, 0, stream>>>(h1, es1, ed1, rowptr, deg, csr, b1, o1elu, n);

    // Layer 2
    k_h2<<<(n * 64 + 255) / 256, 256, 0, stream>>>(o1elu, W2, as2, ad2, h2, es2, ed2, n);
    k_agg2<<<(n + 255) / 256, 256, 0, stream>>>(h2, es2, ed2, rowptr, deg, csr, b2, out, n);
}

// Round 2
// 301.885 us; speedup vs baseline: 1.3607x; 1.3607x over previous
//
#include <hip/hip_runtime.h>
#include <hip/hip_bf16.h>
#include <math.h>

#define NN 50000
#define FIN 48
#define HC 64   // 8 heads x 8 ch
#define NHEAD 8
#define NCH 8
#define NCLS 2
#define NEG 0.2f

// ---------------- CSR build ----------------

__global__ void k_fill(int* deg, int* cursor, int n) {
    int i = blockIdx.x * blockDim.x + threadIdx.x;
    if (i < n) { deg[i] = 1; cursor[i] = 0; }   // 1 = self-loop
}

__global__ void k_count(const int* ei, int* deg, int e) {
    int i = blockIdx.x * blockDim.x + threadIdx.x;
    if (i < e) atomicAdd(&deg[ei[e + i]], 1);   // row 1 = dst
}

#define SCAN_T 256
#define SCAN_E 1024

__global__ void k_scan1(const int* deg, int* bsum, int n) {
    __shared__ int lds[SCAN_T];
    int t = threadIdx.x;
    int base = blockIdx.x * SCAN_E + t * 4;
    int s = 0;
    #pragma unroll
    for (int k = 0; k < 4; ++k) { int idx = base + k; if (idx < n) s += deg[idx]; }
    lds[t] = s;
    __syncthreads();
    for (int off = SCAN_T / 2; off > 0; off >>= 1) {
        if (t < off) lds[t] += lds[t + off];
        __syncthreads();
    }
    if (t == 0) bsum[blockIdx.x] = lds[0];
}

__global__ void k_scan2(int* bsum, int nb) {
    if (threadIdx.x == 0 && blockIdx.x == 0) {
        int acc = 0;
        for (int i = 0; i < nb; ++i) { int v = bsum[i]; bsum[i] = acc; acc += v; }
    }
}

__global__ void k_scan3(const int* deg, const int* bsum, int* rowptr, int n) {
    __shared__ int lds[SCAN_T];
    int t = threadIdx.x;
    int base = blockIdx.x * SCAN_E + t * 4;
    int v[4]; int s = 0;
    #pragma unroll
    for (int k = 0; k < 4; ++k) { int idx = base + k; v[k] = (idx < n) ? deg[idx] : 0; s += v[k]; }
    lds[t] = s;
    __syncthreads();
    for (int off = 1; off < SCAN_T; off <<= 1) {
        int y = (t >= off) ? lds[t - off] : 0;
        __syncthreads();
        lds[t] += y;
        __syncthreads();
    }
    int excl = lds[t] - s + bsum[blockIdx.x];
    #pragma unroll
    for (int k = 0; k < 4; ++k) {
        int idx = base + k;
        if (idx < n) rowptr[idx] = excl;
        excl += v[k];
    }
}

__global__ void k_scatter(const int* ei, const int* rowptr, int* cursor, int* csr,
                          int e, int n) {
    int i = blockIdx.x * blockDim.x + threadIdx.x;
    int tot = e + n;
    if (i >= tot) return;
    int s, d;
    if (i < e) { s = ei[i]; d = ei[e + i]; }
    else       { s = i - e; d = i - e; }       // self-loop
    int pos = atomicAdd(&cursor[d], 1);
    csr[rowptr[d] + pos] = s;
}

// ---------------- Layer 1: h1 = x @ W1 (bf16 out) ; e_src/e_dst ----------------

__global__ void k_h1(const float* __restrict__ x, const float* __restrict__ W1,
                     const float* __restrict__ as1, const float* __restrict__ ad1,
                     __hip_bfloat16* __restrict__ h1b, float* __restrict__ es1,
                     float* __restrict__ ed1, int n) {
    __shared__ float Wl[FIN * HC];
    __shared__ float xs[4][FIN];
    __shared__ float hr[4][HC];
    int tid = threadIdx.x;
    for (int i = tid; i < FIN * HC; i += 256) Wl[i] = W1[i];
    int nb = blockIdx.x * 4;
    for (int i = tid; i < 4 * FIN; i += 256) {
        int nl = i / FIN, k = i % FIN;
        int nd = nb + nl;
        xs[nl][k] = (nd < n) ? x[nd * FIN + k] : 0.f;
    }
    __syncthreads();
    int nl = tid >> 6, j = tid & 63;
    float acc = 0.f;
    #pragma unroll
    for (int k = 0; k < FIN; ++k) acc += xs[nl][k] * Wl[k * HC + j];
    int nd = nb + nl;
    if (nd < n) h1b[nd * HC + j] = __float2bfloat16(acc);
    hr[nl][j] = acc;
    __syncthreads();
    if (j < 16 && nd < n) {
        int hh = j & 7;
        const float* av = (j < 8) ? as1 : ad1;
        float ev = 0.f;
        #pragma unroll
        for (int c = 0; c < NCH; ++c) ev += hr[nl][hh * NCH + c] * av[hh * NCH + c];
        if (j < 8) es1[nd * NHEAD + hh] = ev;
        else       ed1[nd * NHEAD + hh] = ev;
    }
}

// ---------------- Layer 1 aggregation: wave per dst node, online softmax, 4-way unroll ----------------

__global__ void k_agg1(const __hip_bfloat16* __restrict__ h1b, const float* __restrict__ es1,
                       const float* __restrict__ ed1, const int* __restrict__ rowptr,
                       const int* __restrict__ deg, const int* __restrict__ csr,
                       const float* __restrict__ b1, float* __restrict__ o1elu, int n) {
    int wid = (blockIdx.x * blockDim.x + threadIdx.x) >> 6;
    if (wid >= n) return;
    int lane = threadIdx.x & 63;
    int h = lane >> 3;
    int start = rowptr[wid];
    int cnt = deg[wid];
    float edv = ed1[wid * NHEAD + h];
    float m = -3.0e38f, sumw = 0.f, acc = 0.f;
    int i = 0;
    for (; i + 4 <= cnt; i += 4) {
        int s0 = csr[start + i + 0];
        int s1 = csr[start + i + 1];
        int s2 = csr[start + i + 2];
        int s3 = csr[start + i + 3];
        float v0 = es1[s0 * NHEAD + h] + edv; v0 = v0 > 0.f ? v0 : NEG * v0;
        float v1 = es1[s1 * NHEAD + h] + edv; v1 = v1 > 0.f ? v1 : NEG * v1;
        float v2 = es1[s2 * NHEAD + h] + edv; v2 = v2 > 0.f ? v2 : NEG * v2;
        float v3 = es1[s3 * NHEAD + h] + edv; v3 = v3 > 0.f ? v3 : NEG * v3;
        float hv0 = __bfloat162float(h1b[s0 * HC + lane]);
        float hv1 = __bfloat162float(h1b[s1 * HC + lane]);
        float hv2 = __bfloat162float(h1b[s2 * HC + lane]);
        float hv3 = __bfloat162float(h1b[s3 * HC + lane]);
        float nm = fmaxf(fmaxf(fmaxf(v0, v1), fmaxf(v2, v3)), m);
        float sc = __expf(m - nm);
        float w0 = __expf(v0 - nm);
        float w1 = __expf(v1 - nm);
        float w2 = __expf(v2 - nm);
        float w3 = __expf(v3 - nm);
        sumw = sumw * sc + ((w0 + w1) + (w2 + w3));
        acc  = acc  * sc + ((w0 * hv0 + w1 * hv1) + (w2 * hv2 + w3 * hv3));
        m = nm;
    }
    for (; i < cnt; ++i) {
        int s = csr[start + i];
        float val = es1[s * NHEAD + h] + edv;
        val = val > 0.f ? val : NEG * val;
        float hv = __bfloat162float(h1b[s * HC + lane]);
        float nm = fmaxf(m, val);
        float sc = __expf(m - nm);
        float w  = __expf(val - nm);
        sumw = sumw * sc + w;
        acc  = acc  * sc + w * hv;
        m = nm;
    }
    float out = acc / sumw + b1[lane];
    o1elu[wid * HC + lane] = out > 0.f ? out : expm1f(out);   // fused bias + ELU
}

// ---------------- Layer 2: h2 = o1elu @ W2 ; e_src2/e_dst2 ----------------

__global__ void k_h2(const float* __restrict__ o1elu, const float* __restrict__ W2,
                     const float* __restrict__ as2, const float* __restrict__ ad2,
                     float* __restrict__ h2, float* __restrict__ es2,
                     float* __restrict__ ed2, int n) {
    int wid = (blockIdx.x * blockDim.x + threadIdx.x) >> 6;
    if (wid >= n) return;
    int lane = threadIdx.x & 63;
    float v = o1elu[wid * HC + lane];
    float p0 = v * W2[lane * NCLS + 0];
    float p1 = v * W2[lane * NCLS + 1];
    #pragma unroll
    for (int off = 32; off > 0; off >>= 1) {
        p0 += __shfl_xor(p0, off, 64);
        p1 += __shfl_xor(p1, off, 64);
    }
    if (lane == 0) {
        h2[wid * NCLS + 0] = p0;
        h2[wid * NCLS + 1] = p1;
        es2[wid] = p0 * as2[0] + p1 * as2[1];
        ed2[wid] = p0 * ad2[0] + p1 * ad2[1];
    }
}

// ---------------- Layer 2 aggregation: wave per node, lane-parallel edges ----------------

__global__ void k_agg2(const float* __restrict__ h2, const float* __restrict__ es2,
                       const float* __restrict__ ed2, const int* __restrict__ rowptr,
                       const int* __restrict__ deg, const int* __restrict__ csr,
                       const float* __restrict__ b2, float* __restrict__ out, int n) {
    int wid = (blockIdx.x * blockDim.x + threadIdx.x) >> 6;
    if (wid >= n) return;
    int lane = threadIdx.x & 63;
    int start = rowptr[wid];
    int cnt = deg[wid];
    float edv = ed2[wid];
    float m = -3.0e38f, sw = 0.f, a0 = 0.f, a1 = 0.f;
    for (int i = lane; i < cnt; i += 64) {
        int s = csr[start + i];
        float val = es2[s] + edv;
        val = val > 0.f ? val : NEG * val;
        float2 hh = *(const float2*)&h2[s * NCLS];
        float nm = fmaxf(m, val);
        float sc = __expf(m - nm);
        float w  = __expf(val - nm);
        sw = sw * sc + w;
        a0 = a0 * sc + w * hh.x;
        a1 = a1 * sc + w * hh.y;
        m = nm;
    }
    // butterfly combine of online-softmax partials across 64 lanes
    #pragma unroll
    for (int off = 32; off > 0; off >>= 1) {
        float mo  = __shfl_xor(m, off, 64);
        float swo = __shfl_xor(sw, off, 64);
        float a0o = __shfl_xor(a0, off, 64);
        float a1o = __shfl_xor(a1, off, 64);
        float nm = fmaxf(m, mo);
        float sc = __expf(m - nm), so = __expf(mo - nm);
        sw = sw * sc + swo * so;
        a0 = a0 * sc + a0o * so;
        a1 = a1 * sc + a1o * so;
        m = nm;
    }
    if (lane == 0) {
        float z0 = a0 / sw + b2[0];
        float z1 = a1 / sw + b2[1];
        float mz = fmaxf(z0, z1);
        float lse = mz + logf(__expf(z0 - mz) + __expf(z1 - mz));
        out[wid * NCLS + 0] = z0 - lse;
        out[wid * NCLS + 1] = z1 - lse;
    }
}

// ---------------- launch ----------------

extern "C" void kernel_launch(void* const* d_in, const int* in_sizes, int n_in,
                              void* d_out, int out_size, void* d_ws, size_t ws_size,
                              hipStream_t stream) {
    const float* x   = (const float*)d_in[0];
    const int*   ei  = (const int*)d_in[1];
    const float* W1  = (const float*)d_in[2];
    const float* as1 = (const float*)d_in[3];
    const float* ad1 = (const float*)d_in[4];
    const float* b1  = (const float*)d_in[5];
    const float* W2  = (const float*)d_in[6];
    const float* as2 = (const float*)d_in[7];
    const float* ad2 = (const float*)d_in[8];
    const float* b2  = (const float*)d_in[9];
    float* out = (float*)d_out;

    const int n = in_sizes[0] / FIN;     // 50000
    const int e = in_sizes[1] / 2;       // 1600000
    const int ea = e + n;

    char* ws = (char*)d_ws;
    size_t off = 0;
    auto alloc = [&](size_t bytes) -> void* {
        void* p = ws + off;
        off += (bytes + 255) & ~(size_t)255;
        return p;
    };
    __hip_bfloat16* h1b = (__hip_bfloat16*)alloc((size_t)n * HC * 2);
    float* o1elu = (float*)alloc((size_t)n * HC * 4);
    float* es1   = (float*)alloc((size_t)n * NHEAD * 4);
    float* ed1   = (float*)alloc((size_t)n * NHEAD * 4);
    float* h2    = (float*)alloc((size_t)n * NCLS * 4);
    float* es2   = (float*)alloc((size_t)n * 4);
    float* ed2   = (float*)alloc((size_t)n * 4);
    int* deg     = (int*)alloc((size_t)n * 4);
    int* rowptr  = (int*)alloc((size_t)n * 4);
    int* cursor  = (int*)alloc((size_t)n * 4);
    int* bsum    = (int*)alloc(256 * 4);
    int* csr     = (int*)alloc((size_t)ea * 4);

    const int nb_scan = (n + SCAN_E - 1) / SCAN_E;   // 49

    // CSR build
    k_fill<<<(n + 255) / 256, 256, 0, stream>>>(deg, cursor, n);
    k_count<<<(e + 255) / 256, 256, 0, stream>>>(ei, deg, e);
    k_scan1<<<nb_scan, SCAN_T, 0, stream>>>(deg, bsum, n);
    k_scan2<<<1, 64, 0, stream>>>(bsum, nb_scan);
    k_scan3<<<nb_scan, SCAN_T, 0, stream>>>(deg, bsum, rowptr, n);
    k_scatter<<<(ea + 255) / 256, 256, 0, stream>>>(ei, rowptr, cursor, csr, e, n);

    // Layer 1
    k_h1<<<(n + 3) / 4, 256, 0, stream>>>(x, W1, as1, ad1, h1b, es1, ed1, n);
    k_agg1<<<(n * 64 + 255) / 256, 256, 0, stream>>>(h1b, es1, ed1, rowptr, deg, csr, b1, o1elu, n);

    // Layer 2
    k_h2<<<(n * 64 + 255) / 256, 256, 0, stream>>>(o1elu, W2, as2, ad2, h2, es2, ed2, n);
    k_agg2<<<(n * 64 + 255) / 256, 256, 0, stream>>>(h2, es2, ed2, rowptr, deg, csr, b2, out, n);
}

// Round 3
// 191.405 us; speedup vs baseline: 2.1461x; 1.5772x over previous
//
#include <hip/hip_runtime.h>
#include <hip/hip_bf16.h>
#include <math.h>

#define NN 50000
#define FIN 48
#define HC 64   // 8 heads x 8 ch
#define NHEAD 8
#define NCH 8
#define NCLS 2
#define NEG 0.2f

#define NPB 196                        // nodes per bucket
#define NBKT ((NN + NPB - 1) / NPB)    // 256 buckets
#define BCHUNK 4096                    // edges per binning workgroup

// ---------------- CSR build: two-phase bucket sort ----------------

__global__ void k_init(int* bcnt) {
    int t = blockIdx.x * blockDim.x + threadIdx.x;
    if (t < NBKT) bcnt[t] = 0;
}

// histogram of edges (incl. self-loops) over dst-range buckets
__global__ void k_binhist(const int* __restrict__ ei, int* __restrict__ bcnt,
                          int e, int tot) {
    __shared__ int hist[NBKT];
    int t = threadIdx.x;
    hist[t] = 0;
    __syncthreads();
    int base = blockIdx.x * BCHUNK;
    int end = min(base + BCHUNK, tot);
    for (int i = base + t; i < end; i += 256) {
        int d = (i < e) ? ei[e + i] : (i - e);
        atomicAdd(&hist[d / NPB], 1);
    }
    __syncthreads();
    if (hist[t]) atomicAdd(&bcnt[t], hist[t]);
}

__global__ void k_binscan(const int* __restrict__ bcnt, int* __restrict__ bbase,
                          int* __restrict__ bcur) {
    if (threadIdx.x == 0) {
        int acc = 0;
        for (int i = 0; i < NBKT; ++i) { bbase[i] = acc; bcur[i] = acc; acc += bcnt[i]; }
        bbase[NBKT] = acc;
    }
}

// WG-local counting sort: write (src,dst) pairs grouped by bucket
__global__ void k_binwrite(const int* __restrict__ ei, int* __restrict__ bcur,
                           int2* __restrict__ pairs, int e, int tot) {
    __shared__ int hist[NBKT];
    __shared__ int gbase[NBKT];
    int t = threadIdx.x;
    hist[t] = 0;
    __syncthreads();
    int base = blockIdx.x * BCHUNK;
    int end = min(base + BCHUNK, tot);
    for (int i = base + t; i < end; i += 256) {
        int d = (i < e) ? ei[e + i] : (i - e);
        atomicAdd(&hist[d / NPB], 1);
    }
    __syncthreads();
    int h = hist[t];
    gbase[t] = h ? atomicAdd(&bcur[t], h) : 0;
    __syncthreads();
    hist[t] = 0;
    __syncthreads();
    for (int i = base + t; i < end; i += 256) {
        int s, d;
        if (i < e) { s = ei[i]; d = ei[e + i]; }
        else       { s = d = i - e; }
        int b = d / NPB;
        int p = atomicAdd(&hist[b], 1);
        pairs[gbase[b] + p] = make_int2(s, d);
    }
}

// one WG per bucket: LDS degree hist -> scan -> rowptr slice + csr scatter (L2-local)
__global__ void k_bucket_csr(const int2* __restrict__ pairs, const int* __restrict__ bbase,
                             int* __restrict__ rowptr, int* __restrict__ csr,
                             int n, int tot) {
    __shared__ int deg[256];
    __shared__ int cur[256];
    int b = blockIdx.x, t = threadIdx.x;
    int lo = b * NPB;
    int nn = min(NPB, n - lo);
    int base = bbase[b];
    int cnt = bbase[b + 1] - base;
    deg[t] = 0;
    __syncthreads();
    for (int i = t; i < cnt; i += 256) {
        int d = pairs[base + i].y;
        atomicAdd(&deg[d - lo], 1);
    }
    __syncthreads();
    int v = deg[t];
    for (int off = 1; off < 256; off <<= 1) {
        int y = (t >= off) ? deg[t - off] : 0;
        __syncthreads();
        deg[t] += y;
        __syncthreads();
    }
    int excl = deg[t] - v;     // exclusive scan
    if (t < nn) rowptr[lo + t] = base + excl;
    cur[t] = excl;
    if (b == (int)gridDim.x - 1 && t == 0) rowptr[n] = tot;
    __syncthreads();
    for (int i = t; i < cnt; i += 256) {
        int2 p = pairs[base + i];
        int pos = atomicAdd(&cur[p.y - lo], 1);
        csr[base + pos] = p.x;
    }
}

// ---------------- Layer 1: h1 = x @ W1 (bf16 out) ; e_src/e_dst ----------------

__global__ void k_h1(const float* __restrict__ x, const float* __restrict__ W1,
                     const float* __restrict__ as1, const float* __restrict__ ad1,
                     __hip_bfloat16* __restrict__ h1b, float* __restrict__ es1,
                     float* __restrict__ ed1, int n) {
    __shared__ float Wl[FIN * HC];
    __shared__ float xs[4][FIN];
    __shared__ float hr[4][HC];
    int tid = threadIdx.x;
    for (int i = tid; i < FIN * HC; i += 256) Wl[i] = W1[i];
    int nb = blockIdx.x * 4;
    for (int i = tid; i < 4 * FIN; i += 256) {
        int nl = i / FIN, k = i % FIN;
        int nd = nb + nl;
        xs[nl][k] = (nd < n) ? x[nd * FIN + k] : 0.f;
    }
    __syncthreads();
    int nl = tid >> 6, j = tid & 63;
    float acc = 0.f;
    #pragma unroll
    for (int k = 0; k < FIN; ++k) acc += xs[nl][k] * Wl[k * HC + j];
    int nd = nb + nl;
    if (nd < n) h1b[nd * HC + j] = __float2bfloat16(acc);
    hr[nl][j] = acc;
    __syncthreads();
    if (j < 16 && nd < n) {
        int hh = j & 7;
        const float* av = (j < 8) ? as1 : ad1;
        float ev = 0.f;
        #pragma unroll
        for (int c = 0; c < NCH; ++c) ev += hr[nl][hh * NCH + c] * av[hh * NCH + c];
        if (j < 8) es1[nd * NHEAD + hh] = ev;
        else       ed1[nd * NHEAD + hh] = ev;
    }
}

// ---------------- Layer 1 aggregation: wave per dst node, online softmax, 4-way unroll ----------------

__global__ void k_agg1(const __hip_bfloat16* __restrict__ h1b, const float* __restrict__ es1,
                       const float* __restrict__ ed1, const int* __restrict__ rowptr,
                       const int* __restrict__ csr,
                       const float* __restrict__ b1, float* __restrict__ o1elu, int n) {
    int wid = (blockIdx.x * blockDim.x + threadIdx.x) >> 6;
    if (wid >= n) return;
    int lane = threadIdx.x & 63;
    int h = lane >> 3;
    int start = rowptr[wid];
    int cnt = rowptr[wid + 1] - start;
    float edv = ed1[wid * NHEAD + h];
    float m = -3.0e38f, sumw = 0.f, acc = 0.f;
    int i = 0;
    for (; i + 4 <= cnt; i += 4) {
        int s0 = csr[start + i + 0];
        int s1 = csr[start + i + 1];
        int s2 = csr[start + i + 2];
        int s3 = csr[start + i + 3];
        float v0 = es1[s0 * NHEAD + h] + edv; v0 = v0 > 0.f ? v0 : NEG * v0;
        float v1 = es1[s1 * NHEAD + h] + edv; v1 = v1 > 0.f ? v1 : NEG * v1;
        float v2 = es1[s2 * NHEAD + h] + edv; v2 = v2 > 0.f ? v2 : NEG * v2;
        float v3 = es1[s3 * NHEAD + h] + edv; v3 = v3 > 0.f ? v3 : NEG * v3;
        float hv0 = __bfloat162float(h1b[s0 * HC + lane]);
        float hv1 = __bfloat162float(h1b[s1 * HC + lane]);
        float hv2 = __bfloat162float(h1b[s2 * HC + lane]);
        float hv3 = __bfloat162float(h1b[s3 * HC + lane]);
        float nm = fmaxf(fmaxf(fmaxf(v0, v1), fmaxf(v2, v3)), m);
        float sc = __expf(m - nm);
        float w0 = __expf(v0 - nm);
        float w1 = __expf(v1 - nm);
        float w2 = __expf(v2 - nm);
        float w3 = __expf(v3 - nm);
        sumw = sumw * sc + ((w0 + w1) + (w2 + w3));
        acc  = acc  * sc + ((w0 * hv0 + w1 * hv1) + (w2 * hv2 + w3 * hv3));
        m = nm;
    }
    for (; i < cnt; ++i) {
        int s = csr[start + i];
        float val = es1[s * NHEAD + h] + edv;
        val = val > 0.f ? val : NEG * val;
        float hv = __bfloat162float(h1b[s * HC + lane]);
        float nm = fmaxf(m, val);
        float sc = __expf(m - nm);
        float w  = __expf(val - nm);
        sumw = sumw * sc + w;
        acc  = acc  * sc + w * hv;
        m = nm;
    }
    float out = acc / sumw + b1[lane];
    o1elu[wid * HC + lane] = out > 0.f ? out : expm1f(out);   // fused bias + ELU
}

// ---------------- Layer 2: h2 = o1elu @ W2 ; e_src2/e_dst2 ----------------

__global__ void k_h2(const float* __restrict__ o1elu, const float* __restrict__ W2,
                     const float* __restrict__ as2, const float* __restrict__ ad2,
                     float* __restrict__ h2, float* __restrict__ es2,
                     float* __restrict__ ed2, int n) {
    int wid = (blockIdx.x * blockDim.x + threadIdx.x) >> 6;
    if (wid >= n) return;
    int lane = threadIdx.x & 63;
    float v = o1elu[wid * HC + lane];
    float p0 = v * W2[lane * NCLS + 0];
    float p1 = v * W2[lane * NCLS + 1];
    #pragma unroll
    for (int off = 32; off > 0; off >>= 1) {
        p0 += __shfl_xor(p0, off, 64);
        p1 += __shfl_xor(p1, off, 64);
    }
    if (lane == 0) {
        h2[wid * NCLS + 0] = p0;
        h2[wid * NCLS + 1] = p1;
        es2[wid] = p0 * as2[0] + p1 * as2[1];
        ed2[wid] = p0 * ad2[0] + p1 * ad2[1];
    }
}

// ---------------- Layer 2 aggregation: wave per node, lane-parallel edges ----------------

__global__ void k_agg2(const float* __restrict__ h2, const float* __restrict__ es2,
                       const float* __restrict__ ed2, const int* __restrict__ rowptr,
                       const int* __restrict__ csr,
                       const float* __restrict__ b2, float* __restrict__ out, int n) {
    int wid = (blockIdx.x * blockDim.x + threadIdx.x) >> 6;
    if (wid >= n) return;
    int lane = threadIdx.x & 63;
    int start = rowptr[wid];
    int cnt = rowptr[wid + 1] - start;
    float edv = ed2[wid];
    float m = -3.0e38f, sw = 0.f, a0 = 0.f, a1 = 0.f;
    for (int i = lane; i < cnt; i += 64) {
        int s = csr[start + i];
        float val = es2[s] + edv;
        val = val > 0.f ? val : NEG * val;
        float2 hh = *(const float2*)&h2[s * NCLS];
        float nm = fmaxf(m, val);
        float sc = __expf(m - nm);
        float w  = __expf(val - nm);
        sw = sw * sc + w;
        a0 = a0 * sc + w * hh.x;
        a1 = a1 * sc + w * hh.y;
        m = nm;
    }
    #pragma unroll
    for (int off = 32; off > 0; off >>= 1) {
        float mo  = __shfl_xor(m, off, 64);
        float swo = __shfl_xor(sw, off, 64);
        float a0o = __shfl_xor(a0, off, 64);
        float a1o = __shfl_xor(a1, off, 64);
        float nm = fmaxf(m, mo);
        float sc = __expf(m - nm), so = __expf(mo - nm);
        sw = sw * sc + swo * so;
        a0 = a0 * sc + a0o * so;
        a1 = a1 * sc + a1o * so;
        m = nm;
    }
    if (lane == 0) {
        float z0 = a0 / sw + b2[0];
        float z1 = a1 / sw + b2[1];
        float mz = fmaxf(z0, z1);
        float lse = mz + logf(__expf(z0 - mz) + __expf(z1 - mz));
        out[wid * NCLS + 0] = z0 - lse;
        out[wid * NCLS + 1] = z1 - lse;
    }
}

// ---------------- launch ----------------

extern "C" void kernel_launch(void* const* d_in, const int* in_sizes, int n_in,
                              void* d_out, int out_size, void* d_ws, size_t ws_size,
                              hipStream_t stream) {
    const float* x   = (const float*)d_in[0];
    const int*   ei  = (const int*)d_in[1];
    const float* W1  = (const float*)d_in[2];
    const float* as1 = (const float*)d_in[3];
    const float* ad1 = (const float*)d_in[4];
    const float* b1  = (const float*)d_in[5];
    const float* W2  = (const float*)d_in[6];
    const float* as2 = (const float*)d_in[7];
    const float* ad2 = (const float*)d_in[8];
    const float* b2  = (const float*)d_in[9];
    float* out = (float*)d_out;

    const int n = in_sizes[0] / FIN;     // 50000
    const int e = in_sizes[1] / 2;       // 1600000
    const int tot = e + n;               // edges incl. self-loops

    char* ws = (char*)d_ws;
    size_t off = 0;
    auto alloc = [&](size_t bytes) -> void* {
        void* p = ws + off;
        off += (bytes + 255) & ~(size_t)255;
        return p;
    };
    __hip_bfloat16* h1b = (__hip_bfloat16*)alloc((size_t)n * HC * 2);
    // pairs (13.2 MB) aliases o1elu+h2: pairs dead before agg1 writes o1elu
    int2* pairs  = (int2*)alloc((size_t)tot * 8);
    float* o1elu = (float*)pairs;                       // n*HC*4 = 12.8 MB < 13.2 MB
    float* es1   = (float*)alloc((size_t)n * NHEAD * 4);
    float* ed1   = (float*)alloc((size_t)n * NHEAD * 4);
    float* h2    = (float*)alloc((size_t)n * NCLS * 4);
    float* es2   = (float*)alloc((size_t)n * 4);
    float* ed2   = (float*)alloc((size_t)n * 4);
    int* rowptr  = (int*)alloc(((size_t)n + 1) * 4);
    int* bcnt    = (int*)alloc((NBKT + 1) * 4);
    int* bbase   = (int*)alloc((NBKT + 1) * 4);
    int* bcur    = (int*)alloc((NBKT + 1) * 4);
    int* csr     = (int*)alloc((size_t)tot * 4);

    const int nbin = (tot + BCHUNK - 1) / BCHUNK;   // 403

    // CSR build (bucket sort, no global scatter amplification)
    k_init<<<1, NBKT, 0, stream>>>(bcnt);
    k_binhist<<<nbin, 256, 0, stream>>>(ei, bcnt, e, tot);
    k_binscan<<<1, 64, 0, stream>>>(bcnt, bbase, bcur);
    k_binwrite<<<nbin, 256, 0, stream>>>(ei, bcur, pairs, e, tot);
    k_bucket_csr<<<NBKT, 256, 0, stream>>>(pairs, bbase, rowptr, csr, n, tot);

    // Layer 1
    k_h1<<<(n + 3) / 4, 256, 0, stream>>>(x, W1, as1, ad1, h1b, es1, ed1, n);
    k_agg1<<<(n * 64 + 255) / 256, 256, 0, stream>>>(h1b, es1, ed1, rowptr, csr, b1, o1elu, n);

    // Layer 2
    k_h2<<<(n * 64 + 255) / 256, 256, 0, stream>>>(o1elu, W2, as2, ad2, h2, es2, ed2, n);
    k_agg2<<<(n * 64 + 255) / 256, 256, 0, stream>>>(h2, es2, ed2, rowptr, csr, b2, out, n);
}

// Round 4
// 173.125 us; speedup vs baseline: 2.3727x; 1.1056x over previous
//
#include <hip/hip_runtime.h>
#include <hip/hip_bf16.h>
#include <math.h>

#define NN 50000
#define FIN 48
#define HC 64   // 8 heads x 8 ch
#define NHEAD 8
#define NCH 8
#define NCLS 2
#define NEG 0.2f

#define NPB 196                        // nodes per bucket
#define NBKT ((NN + NPB - 1) / NPB)    // 256 buckets
#define BCHUNK 4096                    // edges per binning workgroup

// ---------------- CSR build: two-phase bucket sort ----------------

__global__ void k_init(int* bcnt) {
    int t = blockIdx.x * blockDim.x + threadIdx.x;
    if (t < NBKT) bcnt[t] = 0;
}

__global__ void k_binhist(const int* __restrict__ ei, int* __restrict__ bcnt,
                          int e, int tot) {
    __shared__ int hist[NBKT];
    int t = threadIdx.x;
    hist[t] = 0;
    __syncthreads();
    int base = blockIdx.x * BCHUNK;
    int end = min(base + BCHUNK, tot);
    for (int i = base + t; i < end; i += 256) {
        int d = (i < e) ? ei[e + i] : (i - e);
        atomicAdd(&hist[d / NPB], 1);
    }
    __syncthreads();
    if (hist[t]) atomicAdd(&bcnt[t], hist[t]);
}

__global__ void k_binscan(const int* __restrict__ bcnt, int* __restrict__ bbase,
                          int* __restrict__ bcur) {
    if (threadIdx.x == 0) {
        int acc = 0;
        for (int i = 0; i < NBKT; ++i) { bbase[i] = acc; bcur[i] = acc; acc += bcnt[i]; }
        bbase[NBKT] = acc;
    }
}

// WG-local counting sort: write packed (dloc<<16 | src) grouped by bucket
__global__ void k_binwrite(const int* __restrict__ ei, int* __restrict__ bcur,
                           int* __restrict__ pairs, int e, int tot) {
    __shared__ int hist[NBKT];
    __shared__ int gbase[NBKT];
    int t = threadIdx.x;
    hist[t] = 0;
    __syncthreads();
    int base = blockIdx.x * BCHUNK;
    int end = min(base + BCHUNK, tot);
    for (int i = base + t; i < end; i += 256) {
        int d = (i < e) ? ei[e + i] : (i - e);
        atomicAdd(&hist[d / NPB], 1);
    }
    __syncthreads();
    int h = hist[t];
    gbase[t] = h ? atomicAdd(&bcur[t], h) : 0;
    __syncthreads();
    hist[t] = 0;
    __syncthreads();
    for (int i = base + t; i < end; i += 256) {
        int s, d;
        if (i < e) { s = ei[i]; d = ei[e + i]; }
        else       { s = d = i - e; }
        int b = d / NPB;
        int p = atomicAdd(&hist[b], 1);
        pairs[gbase[b] + p] = ((d - b * NPB) << 16) | s;   // src<65536, dloc<256
    }
}

// one WG per bucket: LDS degree hist -> scan -> rowptr slice + csr scatter (L2-local)
__global__ void k_bucket_csr(const int* __restrict__ pairs, const int* __restrict__ bbase,
                             int* __restrict__ rowptr, int* __restrict__ csr,
                             int n, int tot) {
    __shared__ int deg[256];
    __shared__ int cur[256];
    int b = blockIdx.x, t = threadIdx.x;
    int lo = b * NPB;
    int nn = min(NPB, n - lo);
    int base = bbase[b];
    int cnt = bbase[b + 1] - base;
    deg[t] = 0;
    __syncthreads();
    for (int i = t; i < cnt; i += 256) {
        atomicAdd(&deg[pairs[base + i] >> 16], 1);
    }
    __syncthreads();
    int v = deg[t];
    for (int off = 1; off < 256; off <<= 1) {
        int y = (t >= off) ? deg[t - off] : 0;
        __syncthreads();
        deg[t] += y;
        __syncthreads();
    }
    int excl = deg[t] - v;     // exclusive scan
    if (t < nn) rowptr[lo + t] = base + excl;
    cur[t] = excl;
    if (b == (int)gridDim.x - 1 && t == 0) rowptr[n] = tot;
    __syncthreads();
    for (int i = t; i < cnt; i += 256) {
        int p = pairs[base + i];
        int pos = atomicAdd(&cur[p >> 16], 1);
        csr[base + pos] = p & 0xFFFF;
    }
}

// ---------------- Layer 1: h1 = x @ W1 (bf16 out) ; e_src/e_dst ----------------

__global__ void k_h1(const float* __restrict__ x, const float* __restrict__ W1,
                     const float* __restrict__ as1, const float* __restrict__ ad1,
                     __hip_bfloat16* __restrict__ h1b, float* __restrict__ es1,
                     float* __restrict__ ed1, int n) {
    __shared__ float Wl[FIN * HC];
    __shared__ float xs[4][FIN];
    __shared__ float hr[4][HC];
    int tid = threadIdx.x;
    for (int i = tid; i < FIN * HC; i += 256) Wl[i] = W1[i];
    int nb = blockIdx.x * 4;
    for (int i = tid; i < 4 * FIN; i += 256) {
        int nl = i / FIN, k = i % FIN;
        int nd = nb + nl;
        xs[nl][k] = (nd < n) ? x[nd * FIN + k] : 0.f;
    }
    __syncthreads();
    int nl = tid >> 6, j = tid & 63;
    float acc = 0.f;
    #pragma unroll
    for (int k = 0; k < FIN; ++k) acc += xs[nl][k] * Wl[k * HC + j];
    int nd = nb + nl;
    if (nd < n) h1b[nd * HC + j] = __float2bfloat16(acc);
    hr[nl][j] = acc;
    __syncthreads();
    if (j < 16 && nd < n) {
        int hh = j & 7;
        const float* av = (j < 8) ? as1 : ad1;
        float ev = 0.f;
        #pragma unroll
        for (int c = 0; c < NCH; ++c) ev += hr[nl][hh * NCH + c] * av[hh * NCH + c];
        if (j < 8) es1[nd * NHEAD + hh] = ev;
        else       ed1[nd * NHEAD + hh] = ev;
    }
}

// ---------------- Layer 1 aggregation: wave per dst node, 8 edges/batch,
// lane (h,j) computes weight for (edge j, head h) exactly once ----------------

__global__ void k_agg1(const __hip_bfloat16* __restrict__ h1b, const float* __restrict__ es1,
                       const float* __restrict__ ed1, const int* __restrict__ rowptr,
                       const int* __restrict__ csr,
                       const float* __restrict__ b1, float* __restrict__ o1elu, int n) {
    int wid = (blockIdx.x * blockDim.x + threadIdx.x) >> 6;
    if (wid >= n) return;
    int lane = threadIdx.x & 63;
    int j  = lane & 7;    // edge slot within batch
    int hh = lane >> 3;   // head (for weight AND accumulation roles)
    int lb = lane & 56;   // base lane of this head's group
    int start = rowptr[wid];
    int cnt = rowptr[wid + 1] - start;
    int last = start + cnt - 1;
    float edv = ed1[wid * NHEAD + hh];
    float m = -3.0e38f, sumw = 0.f, acc = 0.f;
    for (int i = 0; i < cnt; i += 8) {
        int idx = start + i + j;
        int sl = csr[idx > last ? last : idx];
        float ev = es1[sl * NHEAD + hh] + edv;
        ev = ev > 0.f ? ev : NEG * ev;
        float v = (i + j < cnt) ? ev : -3.0e38f;   // pad -> w=0
        // max over the 8 edge-slots within this head's lane group
        float gm = fmaxf(v, __shfl_xor(v, 1, 64));
        gm = fmaxf(gm, __shfl_xor(gm, 2, 64));
        gm = fmaxf(gm, __shfl_xor(gm, 4, 64));
        float nm = fmaxf(m, gm);
        float sc = __expf(m - nm);
        float w  = __expf(v - nm);                  // weight for (edge j, head hh)
        float ws = w + __shfl_xor(w, 1, 64);
        ws += __shfl_xor(ws, 2, 64);
        ws += __shfl_xor(ws, 4, 64);
        sumw = sumw * sc + ws;
        acc *= sc;
        #pragma unroll
        for (int jj = 0; jj < 8; ++jj) {
            int su   = __builtin_amdgcn_readlane(sl, jj);      // uniform src id
            float wj = __shfl(w, lb + jj, 64);                 // weight (jj, hh)
            float hv = __bfloat162float(h1b[su * HC + lane]);
            acc += wj * hv;
        }
        m = nm;
    }
    float outv = acc / sumw + b1[lane];
    o1elu[wid * HC + lane] = outv > 0.f ? outv : expm1f(outv);   // fused bias + ELU
}

// ---------------- Layer 2: h2 = o1elu @ W2 ; e_src2/e_dst2 ----------------

__global__ void k_h2(const float* __restrict__ o1elu, const float* __restrict__ W2,
                     const float* __restrict__ as2, const float* __restrict__ ad2,
                     float* __restrict__ h2, float* __restrict__ es2,
                     float* __restrict__ ed2, int n) {
    int wid = (blockIdx.x * blockDim.x + threadIdx.x) >> 6;
    if (wid >= n) return;
    int lane = threadIdx.x & 63;
    float v = o1elu[wid * HC + lane];
    float p0 = v * W2[lane * NCLS + 0];
    float p1 = v * W2[lane * NCLS + 1];
    #pragma unroll
    for (int off = 32; off > 0; off >>= 1) {
        p0 += __shfl_xor(p0, off, 64);
        p1 += __shfl_xor(p1, off, 64);
    }
    if (lane == 0) {
        h2[wid * NCLS + 0] = p0;
        h2[wid * NCLS + 1] = p1;
        es2[wid] = p0 * as2[0] + p1 * as2[1];
        ed2[wid] = p0 * ad2[0] + p1 * ad2[1];
    }
}

// ---------------- Layer 2 aggregation: wave per node, lane-parallel edges ----------------

__global__ void k_agg2(const float* __restrict__ h2, const float* __restrict__ es2,
                       const float* __restrict__ ed2, const int* __restrict__ rowptr,
                       const int* __restrict__ csr,
                       const float* __restrict__ b2, float* __restrict__ out, int n) {
    int wid = (blockIdx.x * blockDim.x + threadIdx.x) >> 6;
    if (wid >= n) return;
    int lane = threadIdx.x & 63;
    int start = rowptr[wid];
    int cnt = rowptr[wid + 1] - start;
    float edv = ed2[wid];
    float m = -3.0e38f, sw = 0.f, a0 = 0.f, a1 = 0.f;
    for (int i = lane; i < cnt; i += 64) {
        int s = csr[start + i];
        float val = es2[s] + edv;
        val = val > 0.f ? val : NEG * val;
        float2 hh = *(const float2*)&h2[s * NCLS];
        float nm = fmaxf(m, val);
        float sc = __expf(m - nm);
        float w  = __expf(val - nm);
        sw = sw * sc + w;
        a0 = a0 * sc + w * hh.x;
        a1 = a1 * sc + w * hh.y;
        m = nm;
    }
    #pragma unroll
    for (int off = 32; off > 0; off >>= 1) {
        float mo  = __shfl_xor(m, off, 64);
        float swo = __shfl_xor(sw, off, 64);
        float a0o = __shfl_xor(a0, off, 64);
        float a1o = __shfl_xor(a1, off, 64);
        float nm = fmaxf(m, mo);
        float sc = __expf(m - nm), so = __expf(mo - nm);
        sw = sw * sc + swo * so;
        a0 = a0 * sc + a0o * so;
        a1 = a1 * sc + a1o * so;
        m = nm;
    }
    if (lane == 0) {
        float z0 = a0 / sw + b2[0];
        float z1 = a1 / sw + b2[1];
        float mz = fmaxf(z0, z1);
        float lse = mz + logf(__expf(z0 - mz) + __expf(z1 - mz));
        out[wid * NCLS + 0] = z0 - lse;
        out[wid * NCLS + 1] = z1 - lse;
    }
}

// ---------------- launch ----------------

extern "C" void kernel_launch(void* const* d_in, const int* in_sizes, int n_in,
                              void* d_out, int out_size, void* d_ws, size_t ws_size,
                              hipStream_t stream) {
    const float* x   = (const float*)d_in[0];
    const int*   ei  = (const int*)d_in[1];
    const float* W1  = (const float*)d_in[2];
    const float* as1 = (const float*)d_in[3];
    const float* ad1 = (const float*)d_in[4];
    const float* b1  = (const float*)d_in[5];
    const float* W2  = (const float*)d_in[6];
    const float* as2 = (const float*)d_in[7];
    const float* ad2 = (const float*)d_in[8];
    const float* b2  = (const float*)d_in[9];
    float* out = (float*)d_out;

    const int n = in_sizes[0] / FIN;     // 50000
    const int e = in_sizes[1] / 2;       // 1600000
    const int tot = e + n;               // edges incl. self-loops

    char* ws = (char*)d_ws;
    size_t off = 0;
    auto alloc = [&](size_t bytes) -> void* {
        void* p = ws + off;
        off += (bytes + 255) & ~(size_t)255;
        return p;
    };
    __hip_bfloat16* h1b = (__hip_bfloat16*)alloc((size_t)n * HC * 2);
    // pairs (6.6 MB) aliases o1elu: pairs dead before agg1 writes o1elu
    float* o1elu = (float*)alloc((size_t)n * HC * 4);
    int* pairs   = (int*)o1elu;
    float* es1   = (float*)alloc((size_t)n * NHEAD * 4);
    float* ed1   = (float*)alloc((size_t)n * NHEAD * 4);
    float* h2    = (float*)alloc((size_t)n * NCLS * 4);
    float* es2   = (float*)alloc((size_t)n * 4);
    float* ed2   = (float*)alloc((size_t)n * 4);
    int* rowptr  = (int*)alloc(((size_t)n + 1) * 4);
    int* bcnt    = (int*)alloc((NBKT + 1) * 4);
    int* bbase   = (int*)alloc((NBKT + 1) * 4);
    int* bcur    = (int*)alloc((NBKT + 1) * 4);
    int* csr     = (int*)alloc((size_t)tot * 4);

    const int nbin = (tot + BCHUNK - 1) / BCHUNK;   // 403

    // CSR build (bucket sort, no global scatter amplification)
    k_init<<<1, NBKT, 0, stream>>>(bcnt);
    k_binhist<<<nbin, 256, 0, stream>>>(ei, bcnt, e, tot);
    k_binscan<<<1, 64, 0, stream>>>(bcnt, bbase, bcur);
    k_binwrite<<<nbin, 256, 0, stream>>>(ei, bcur, pairs, e, tot);
    k_bucket_csr<<<NBKT, 256, 0, stream>>>(pairs, bbase, rowptr, csr, n, tot);

    // Layer 1
    k_h1<<<(n + 3) / 4, 256, 0, stream>>>(x, W1, as1, ad1, h1b, es1, ed1, n);
    k_agg1<<<(n * 64 + 255) / 256, 256, 0, stream>>>(h1b, es1, ed1, rowptr, csr, b1, o1elu, n);

    // Layer 2
    k_h2<<<(n * 64 + 255) / 256, 256, 0, stream>>>(o1elu, W2, as2, ad2, h2, es2, ed2, n);
    k_agg2<<<(n * 64 + 255) / 256, 256, 0, stream>>>(h2, es2, ed2, rowptr, csr, b2, out, n);
}

// Round 5
// 158.710 us; speedup vs baseline: 2.5882x; 1.0908x over previous
//
#include <hip/hip_runtime.h>
#include <hip/hip_bf16.h>
#include <math.h>

#define NN 50000
#define FIN 48
#define HC 64   // 8 heads x 8 ch
#define NHEAD 8
#define NCH 8
#define NCLS 2
#define NEG 0.2f
#define LOG2E 1.44269504f

#define NPB 196                        // nodes per bucket
#define NBKT ((NN + NPB - 1) / NPB)    // 256 buckets
#define BCHUNK 4096                    // edges per binning workgroup

// ---------------- CSR build: two-phase bucket sort ----------------

__global__ void k_init(int* bcnt) {
    int t = blockIdx.x * blockDim.x + threadIdx.x;
    if (t < NBKT) bcnt[t] = 0;
}

__global__ void k_binhist(const int* __restrict__ ei, int* __restrict__ bcnt,
                          int e, int tot) {
    __shared__ int hist[NBKT];
    int t = threadIdx.x;
    hist[t] = 0;
    __syncthreads();
    int base = blockIdx.x * BCHUNK;
    int end = min(base + BCHUNK, tot);
    for (int i = base + t; i < end; i += 256) {
        int d = (i < e) ? ei[e + i] : (i - e);
        atomicAdd(&hist[d / NPB], 1);
    }
    __syncthreads();
    if (hist[t]) atomicAdd(&bcnt[t], hist[t]);
}

__global__ void k_binscan(const int* __restrict__ bcnt, int* __restrict__ bbase,
                          int* __restrict__ bcur) {
    if (threadIdx.x == 0) {
        int acc = 0;
        for (int i = 0; i < NBKT; ++i) { bbase[i] = acc; bcur[i] = acc; acc += bcnt[i]; }
        bbase[NBKT] = acc;
    }
}

// WG-local counting sort: write packed (dloc<<16 | src) grouped by bucket
__global__ void k_binwrite(const int* __restrict__ ei, int* __restrict__ bcur,
                           int* __restrict__ pairs, int e, int tot) {
    __shared__ int hist[NBKT];
    __shared__ int gbase[NBKT];
    int t = threadIdx.x;
    hist[t] = 0;
    __syncthreads();
    int base = blockIdx.x * BCHUNK;
    int end = min(base + BCHUNK, tot);
    for (int i = base + t; i < end; i += 256) {
        int d = (i < e) ? ei[e + i] : (i - e);
        atomicAdd(&hist[d / NPB], 1);
    }
    __syncthreads();
    int h = hist[t];
    gbase[t] = h ? atomicAdd(&bcur[t], h) : 0;
    __syncthreads();
    hist[t] = 0;
    __syncthreads();
    for (int i = base + t; i < end; i += 256) {
        int s, d;
        if (i < e) { s = ei[i]; d = ei[e + i]; }
        else       { s = d = i - e; }
        int b = d / NPB;
        int p = atomicAdd(&hist[b], 1);
        pairs[gbase[b] + p] = ((d - b * NPB) << 16) | s;   // src<65536, dloc<256
    }
}

// one WG per bucket: LDS degree hist -> scan -> rowptr slice + csr scatter (L2-local)
__global__ void k_bucket_csr(const int* __restrict__ pairs, const int* __restrict__ bbase,
                             int* __restrict__ rowptr, int* __restrict__ csr,
                             int n, int tot) {
    __shared__ int deg[256];
    __shared__ int cur[256];
    int b = blockIdx.x, t = threadIdx.x;
    int lo = b * NPB;
    int nn = min(NPB, n - lo);
    int base = bbase[b];
    int cnt = bbase[b + 1] - base;
    deg[t] = 0;
    __syncthreads();
    for (int i = t; i < cnt; i += 256) {
        atomicAdd(&deg[pairs[base + i] >> 16], 1);
    }
    __syncthreads();
    int v = deg[t];
    for (int off = 1; off < 256; off <<= 1) {
        int y = (t >= off) ? deg[t - off] : 0;
        __syncthreads();
        deg[t] += y;
        __syncthreads();
    }
    int excl = deg[t] - v;     // exclusive scan
    if (t < nn) rowptr[lo + t] = base + excl;
    cur[t] = excl;
    if (b == (int)gridDim.x - 1 && t == 0) rowptr[n] = tot;
    __syncthreads();
    for (int i = t; i < cnt; i += 256) {
        int p = pairs[base + i];
        int pos = atomicAdd(&cur[p >> 16], 1);
        csr[base + pos] = p & 0xFFFF;
    }
}

// ---------------- Layer 1: h1 = x @ W1 (bf16 out) ; e_src/e_dst (pre-scaled by 1/ln2) ----------------

__global__ void k_h1(const float* __restrict__ x, const float* __restrict__ W1,
                     const float* __restrict__ as1, const float* __restrict__ ad1,
                     __hip_bfloat16* __restrict__ h1b, float* __restrict__ es1,
                     float* __restrict__ ed1, int n) {
    __shared__ float Wl[FIN * HC];
    __shared__ float xs[4][FIN];
    __shared__ float hr[4][HC];
    int tid = threadIdx.x;
    for (int i = tid; i < FIN * HC; i += 256) Wl[i] = W1[i];
    int nb = blockIdx.x * 4;
    for (int i = tid; i < 4 * FIN; i += 256) {
        int nl = i / FIN, k = i % FIN;
        int nd = nb + nl;
        xs[nl][k] = (nd < n) ? x[nd * FIN + k] : 0.f;
    }
    __syncthreads();
    int nl = tid >> 6, j = tid & 63;
    float acc = 0.f;
    #pragma unroll
    for (int k = 0; k < FIN; ++k) acc += xs[nl][k] * Wl[k * HC + j];
    int nd = nb + nl;
    if (nd < n) h1b[nd * HC + j] = __float2bfloat16(acc);
    hr[nl][j] = acc;
    __syncthreads();
    if (j < 16 && nd < n) {
        int hh = j & 7;
        const float* av = (j < 8) ? as1 : ad1;
        float ev = 0.f;
        #pragma unroll
        for (int c = 0; c < NCH; ++c) ev += hr[nl][hh * NCH + c] * av[hh * NCH + c];
        ev *= LOG2E;   // pre-scale so agg1 uses raw exp2
        if (j < 8) es1[nd * NHEAD + hh] = ev;
        else       ed1[nd * NHEAD + hh] = ev;
    }
}

// ---------------- Layer 1 aggregation + fused layer-2 linear ----------------
// wave per dst node; lane (hh,j) computes weight of (edge j, head hh) once;
// no max-tracking (logits tiny; exact softmax unchanged); epilogue computes
// bias+ELU then h2 = o1elu @ W2, es2/ed2 -> packed float4 node2.

__global__ void k_agg1(const __hip_bfloat16* __restrict__ h1b, const float* __restrict__ es1,
                       const float* __restrict__ ed1, const int* __restrict__ rowptr,
                       const int* __restrict__ csr, const float* __restrict__ b1,
                       const float* __restrict__ W2, const float* __restrict__ as2,
                       const float* __restrict__ ad2, float4* __restrict__ node2, int n) {
    int wid = (blockIdx.x * blockDim.x + threadIdx.x) >> 6;
    if (wid >= n) return;
    int lane = threadIdx.x & 63;
    int j  = lane & 7;    // edge slot
    int hh = lane >> 3;   // head
    int lb = lane & 56;   // base lane of this head's group
    int start = rowptr[wid];
    int cnt = rowptr[wid + 1] - start;
    float edv = ed1[wid * NHEAD + hh];
    float sumw = 0.f, acc = 0.f;
    int i = 0;
    for (; i + 8 <= cnt; i += 8) {          // full batches: no validity checks
        int sl = csr[start + i + j];
        float ev = es1[sl * NHEAD + hh] + edv;
        ev = fmaxf(ev, NEG * ev);           // leaky_relu
        float w = exp2f(ev);
        sumw += w;
        #pragma unroll
        for (int jj = 0; jj < 8; ++jj) {
            int su   = __builtin_amdgcn_readlane(sl, jj);
            float wj = __shfl(w, lb + jj, 64);
            acc += wj * __bfloat162float(h1b[su * HC + lane]);
        }
    }
    if (i < cnt) {                           // tail batch (peeled)
        int last = start + cnt - 1;
        int idx = start + i + j;
        int sl = csr[idx > last ? last : idx];
        float ev = es1[sl * NHEAD + hh] + edv;
        ev = fmaxf(ev, NEG * ev);
        float w = (i + j < cnt) ? exp2f(ev) : 0.f;
        sumw += w;
        #pragma unroll
        for (int jj = 0; jj < 8; ++jj) {
            int su   = __builtin_amdgcn_readlane(sl, jj);
            float wj = __shfl(w, lb + jj, 64);
            acc += wj * __bfloat162float(h1b[su * HC + lane]);
        }
    }
    // denominator: reduce edge-slot partials within the head's 8-lane group
    sumw += __shfl_xor(sumw, 1, 64);
    sumw += __shfl_xor(sumw, 2, 64);
    sumw += __shfl_xor(sumw, 4, 64);
    float outv = acc / sumw + b1[lane];
    outv = outv > 0.f ? outv : expm1f(outv);          // fused bias + ELU
    // fused layer-2 linear: h2[c] = sum_lane outv * W2[lane][c]
    float p0 = outv * W2[lane * NCLS + 0];
    float p1 = outv * W2[lane * NCLS + 1];
    #pragma unroll
    for (int off = 32; off > 0; off >>= 1) {
        p0 += __shfl_xor(p0, off, 64);
        p1 += __shfl_xor(p1, off, 64);
    }
    if (lane == 0) {
        float es2v = (p0 * as2[0] + p1 * as2[1]) * LOG2E;
        float ed2v = (p0 * ad2[0] + p1 * ad2[1]) * LOG2E;
        node2[wid] = make_float4(es2v, p0, p1, ed2v);
    }
}

// ---------------- Layer 2 aggregation + bias + log_softmax ----------------
// wave per node, lane-parallel edges, single packed float4 load per edge.

__global__ void k_agg2(const float4* __restrict__ node2, const int* __restrict__ rowptr,
                       const int* __restrict__ csr, const float* __restrict__ b2,
                       float* __restrict__ out, int n) {
    int wid = (blockIdx.x * blockDim.x + threadIdx.x) >> 6;
    if (wid >= n) return;
    int lane = threadIdx.x & 63;
    int start = rowptr[wid];
    int cnt = rowptr[wid + 1] - start;
    float edv = ((const float*)node2)[wid * 4 + 3];
    float sw = 0.f, a0 = 0.f, a1 = 0.f;
    for (int i = lane; i < cnt; i += 64) {
        int s = csr[start + i];
        float4 t = node2[s];
        float val = t.x + edv;
        val = fmaxf(val, NEG * val);
        float w = exp2f(val);
        sw += w;
        a0 += w * t.y;
        a1 += w * t.z;
    }
    #pragma unroll
    for (int off = 32; off > 0; off >>= 1) {
        sw += __shfl_xor(sw, off, 64);
        a0 += __shfl_xor(a0, off, 64);
        a1 += __shfl_xor(a1, off, 64);
    }
    if (lane == 0) {
        float z0 = a0 / sw + b2[0];
        float z1 = a1 / sw + b2[1];
        float mz = fmaxf(z0, z1);
        float lse = mz + logf(__expf(z0 - mz) + __expf(z1 - mz));
        out[wid * NCLS + 0] = z0 - lse;
        out[wid * NCLS + 1] = z1 - lse;
    }
}

// ---------------- launch ----------------

extern "C" void kernel_launch(void* const* d_in, const int* in_sizes, int n_in,
                              void* d_out, int out_size, void* d_ws, size_t ws_size,
                              hipStream_t stream) {
    const float* x   = (const float*)d_in[0];
    const int*   ei  = (const int*)d_in[1];
    const float* W1  = (const float*)d_in[2];
    const float* as1 = (const float*)d_in[3];
    const float* ad1 = (const float*)d_in[4];
    const float* b1  = (const float*)d_in[5];
    const float* W2  = (const float*)d_in[6];
    const float* as2 = (const float*)d_in[7];
    const float* ad2 = (const float*)d_in[8];
    const float* b2  = (const float*)d_in[9];
    float* out = (float*)d_out;

    const int n = in_sizes[0] / FIN;     // 50000
    const int e = in_sizes[1] / 2;       // 1600000
    const int tot = e + n;               // edges incl. self-loops

    char* ws = (char*)d_ws;
    size_t off = 0;
    auto alloc = [&](size_t bytes) -> void* {
        void* p = ws + off;
        off += (bytes + 255) & ~(size_t)255;
        return p;
    };
    __hip_bfloat16* h1b = (__hip_bfloat16*)alloc((size_t)n * HC * 2);
    int* pairs   = (int*)alloc((size_t)tot * 4);
    float* es1   = (float*)alloc((size_t)n * NHEAD * 4);
    float* ed1   = (float*)alloc((size_t)n * NHEAD * 4);
    float4* node2 = (float4*)alloc((size_t)n * 16);
    int* rowptr  = (int*)alloc(((size_t)n + 1) * 4);
    int* bcnt    = (int*)alloc((NBKT + 1) * 4);
    int* bbase   = (int*)alloc((NBKT + 1) * 4);
    int* bcur    = (int*)alloc((NBKT + 1) * 4);
    int* csr     = (int*)alloc((size_t)tot * 4);

    const int nbin = (tot + BCHUNK - 1) / BCHUNK;   // 403

    // CSR build (bucket sort, no global scatter amplification)
    k_init<<<1, NBKT, 0, stream>>>(bcnt);
    k_binhist<<<nbin, 256, 0, stream>>>(ei, bcnt, e, tot);
    k_binscan<<<1, 64, 0, stream>>>(bcnt, bbase, bcur);
    k_binwrite<<<nbin, 256, 0, stream>>>(ei, bcur, pairs, e, tot);
    k_bucket_csr<<<NBKT, 256, 0, stream>>>(pairs, bbase, rowptr, csr, n, tot);

    // Layer 1 (+ fused layer-2 linear in agg1 epilogue)
    k_h1<<<(n + 3) / 4, 256, 0, stream>>>(x, W1, as1, ad1, h1b, es1, ed1, n);
    k_agg1<<<(n * 64 + 255) / 256, 256, 0, stream>>>(h1b, es1, ed1, rowptr, csr,
                                                     b1, W2, as2, ad2, node2, n);

    // Layer 2 aggregation
    k_agg2<<<(n * 64 + 255) / 256, 256, 0, stream>>>(node2, rowptr, csr, b2, out, n);
}

// Round 6
// 133.975 us; speedup vs baseline: 3.0660x; 1.1846x over previous
//
#include <hip/hip_runtime.h>
#include <hip/hip_bf16.h>
#include <math.h>

#define NN 50000
#define FIN 48
#define HC 64   // 8 heads x 8 ch
#define NHEAD 8
#define NCH 8
#define NCLS 2
#define NEG 0.2f
#define LOG2E 1.44269504f

#define NPB 196                        // nodes per bucket
#define NBKT ((NN + NPB - 1) / NPB)    // 256 buckets
#define CAP 8192                       // fixed slot capacity per bucket (E[fill]=6450, +21 sigma)
#define BCHUNK 4096                    // edges per binning workgroup

// ---------------- CSR build: single-pass bucket sort into fixed-capacity slots ----------------

// WG-local counting sort: write packed (dloc<<16 | src) into bucket slot b*CAP + offset
__global__ void k_binwrite(const int* __restrict__ ei, int* __restrict__ bcur,
                           int* __restrict__ pairs, int e, int tot) {
    __shared__ int hist[NBKT];
    __shared__ int gbase[NBKT];
    int t = threadIdx.x;
    hist[t] = 0;
    __syncthreads();
    int base = blockIdx.x * BCHUNK;
    int end = min(base + BCHUNK, tot);
    for (int i = base + t; i < end; i += 256) {
        int d = (i < e) ? ei[e + i] : (i - e);
        atomicAdd(&hist[d / NPB], 1);
    }
    __syncthreads();
    int h = hist[t];
    gbase[t] = h ? atomicAdd(&bcur[t], h) : 0;
    __syncthreads();
    hist[t] = 0;
    __syncthreads();
    for (int i = base + t; i < end; i += 256) {
        int s, d;
        if (i < e) { s = ei[i]; d = ei[e + i]; }
        else       { s = d = i - e; }
        int b = d / NPB;
        int p = gbase[b] + atomicAdd(&hist[b], 1);
        if (p < CAP) pairs[b * CAP + p] = ((d - b * NPB) << 16) | s;
    }
}

// one WG per bucket: LDS degree hist -> scan -> rowptr/deg + csr scatter (L2-local)
__global__ void k_bucket_csr(const int* __restrict__ pairs, const int* __restrict__ bcur,
                             int* __restrict__ rowptr, int* __restrict__ degv,
                             int* __restrict__ csr, int n) {
    __shared__ int deg[256];
    __shared__ int cur[256];
    int b = blockIdx.x, t = threadIdx.x;
    int lo = b * NPB;
    int nn = min(NPB, n - lo);
    int base = b * CAP;
    int cnt = min(bcur[b], CAP);
    deg[t] = 0;
    __syncthreads();
    for (int i = t; i < cnt; i += 256) {
        atomicAdd(&deg[pairs[base + i] >> 16], 1);
    }
    __syncthreads();
    int v = deg[t];
    for (int off = 1; off < 256; off <<= 1) {
        int y = (t >= off) ? deg[t - off] : 0;
        __syncthreads();
        deg[t] += y;
        __syncthreads();
    }
    int excl = deg[t] - v;     // exclusive scan
    if (t < nn) { rowptr[lo + t] = base + excl; degv[lo + t] = v; }
    cur[t] = excl;
    __syncthreads();
    for (int i = t; i < cnt; i += 256) {
        int p = pairs[base + i];
        int pos = atomicAdd(&cur[p >> 16], 1);
        csr[base + pos] = p & 0xFFFF;
    }
}

// ---------------- Layer 1: h1 = x @ W1 (bf16 out) ; e_src/e_dst (pre-scaled by 1/ln2) ----------------
// grid-stride: W1 loaded once per block, not once per 4 nodes

__global__ void k_h1(const float* __restrict__ x, const float* __restrict__ W1,
                     const float* __restrict__ as1, const float* __restrict__ ad1,
                     __hip_bfloat16* __restrict__ h1b, float* __restrict__ es1,
                     float* __restrict__ ed1, int n) {
    __shared__ float Wl[FIN * HC];
    __shared__ float xs[4][FIN];
    __shared__ float hr[4][HC];
    int tid = threadIdx.x;
    for (int i = tid; i < FIN * HC; i += 256) Wl[i] = W1[i];
    int ngroups = (n + 3) >> 2;
    int nl = tid >> 6, j = tid & 63;
    for (int g = blockIdx.x; g < ngroups; g += gridDim.x) {
        int nb = g * 4;
        __syncthreads();                 // protect xs/hr from previous iteration
        for (int i = tid; i < 4 * FIN; i += 256) {
            int l = i / FIN, k = i % FIN;
            int nd = nb + l;
            xs[l][k] = (nd < n) ? x[nd * FIN + k] : 0.f;
        }
        __syncthreads();
        float acc = 0.f;
        #pragma unroll
        for (int k = 0; k < FIN; ++k) acc += xs[nl][k] * Wl[k * HC + j];
        int nd = nb + nl;
        if (nd < n) h1b[nd * HC + j] = __float2bfloat16(acc);
        hr[nl][j] = acc;
        __syncthreads();
        if (j < 16 && nd < n) {
            int hh = j & 7;
            const float* av = (j < 8) ? as1 : ad1;
            float ev = 0.f;
            #pragma unroll
            for (int c = 0; c < NCH; ++c) ev += hr[nl][hh * NCH + c] * av[hh * NCH + c];
            ev *= LOG2E;   // pre-scale so agg uses raw exp2
            if (j < 8) es1[nd * NHEAD + hh] = ev;
            else       ed1[nd * NHEAD + hh] = ev;
        }
    }
}

// ---------------- Layer 1 aggregation + fused layer-2 linear ----------------

__global__ void k_agg1(const __hip_bfloat16* __restrict__ h1b, const float* __restrict__ es1,
                       const float* __restrict__ ed1, const int* __restrict__ rowptr,
                       const int* __restrict__ degv, const int* __restrict__ csr,
                       const float* __restrict__ b1,
                       const float* __restrict__ W2, const float* __restrict__ as2,
                       const float* __restrict__ ad2, float4* __restrict__ node2, int n) {
    int wid = (blockIdx.x * blockDim.x + threadIdx.x) >> 6;
    if (wid >= n) return;
    int lane = threadIdx.x & 63;
    int j  = lane & 7;    // edge slot
    int hh = lane >> 3;   // head
    int lb = lane & 56;   // base lane of this head's group
    int start = rowptr[wid];
    int cnt = degv[wid];
    float edv = ed1[wid * NHEAD + hh];
    float sumw = 0.f, acc = 0.f;
    int i = 0;
    for (; i + 8 <= cnt; i += 8) {          // full batches: no validity checks
        int sl = csr[start + i + j];
        float ev = es1[sl * NHEAD + hh] + edv;
        ev = fmaxf(ev, NEG * ev);           // leaky_relu (logits pre-scaled by 1/ln2)
        float w = exp2f(ev);
        sumw += w;
        #pragma unroll
        for (int jj = 0; jj < 8; ++jj) {
            int su   = __builtin_amdgcn_readlane(sl, jj);
            float wj = __shfl(w, lb + jj, 64);
            acc += wj * __bfloat162float(h1b[su * HC + lane]);
        }
    }
    if (i < cnt) {                           // tail batch (peeled)
        int last = start + cnt - 1;
        int idx = start + i + j;
        int sl = csr[idx > last ? last : idx];
        float ev = es1[sl * NHEAD + hh] + edv;
        ev = fmaxf(ev, NEG * ev);
        float w = (i + j < cnt) ? exp2f(ev) : 0.f;
        sumw += w;
        #pragma unroll
        for (int jj = 0; jj < 8; ++jj) {
            int su   = __builtin_amdgcn_readlane(sl, jj);
            float wj = __shfl(w, lb + jj, 64);
            acc += wj * __bfloat162float(h1b[su * HC + lane]);
        }
    }
    // denominator: reduce edge-slot partials within the head's 8-lane group
    sumw += __shfl_xor(sumw, 1, 64);
    sumw += __shfl_xor(sumw, 2, 64);
    sumw += __shfl_xor(sumw, 4, 64);
    float outv = acc / sumw + b1[lane];
    outv = outv > 0.f ? outv : expm1f(outv);          // fused bias + ELU
    // fused layer-2 linear: h2[c] = sum_lane outv * W2[lane][c]
    float p0 = outv * W2[lane * NCLS + 0];
    float p1 = outv * W2[lane * NCLS + 1];
    #pragma unroll
    for (int off = 32; off > 0; off >>= 1) {
        p0 += __shfl_xor(p0, off, 64);
        p1 += __shfl_xor(p1, off, 64);
    }
    if (lane == 0) {
        float es2v = (p0 * as2[0] + p1 * as2[1]) * LOG2E;
        float ed2v = (p0 * ad2[0] + p1 * ad2[1]) * LOG2E;
        node2[wid] = make_float4(es2v, p0, p1, ed2v);
    }
}

// ---------------- Layer 2 aggregation + bias + log_softmax ----------------
// 16-lane segment per node (avg deg 33 -> ~2 iters), 4 nodes per wave

__global__ void k_agg2(const float4* __restrict__ node2, const int* __restrict__ rowptr,
                       const int* __restrict__ degv, const int* __restrict__ csr,
                       const float* __restrict__ b2, float* __restrict__ out, int n) {
    int lane = threadIdx.x & 63;
    int wid = ((blockIdx.x * blockDim.x + threadIdx.x) >> 6) * 4 + (lane >> 4);
    if (wid >= n) return;
    int l16 = lane & 15;
    int start = rowptr[wid];
    int cnt = degv[wid];
    float edv = ((const float*)node2)[wid * 4 + 3];
    float sw = 0.f, a0 = 0.f, a1 = 0.f;
    for (int i = l16; i < cnt; i += 16) {
        int s = csr[start + i];
        float4 t = node2[s];
        float val = t.x + edv;
        val = fmaxf(val, NEG * val);
        float w = exp2f(val);
        sw += w;
        a0 += w * t.y;
        a1 += w * t.z;
    }
    #pragma unroll
    for (int off = 8; off > 0; off >>= 1) {
        sw += __shfl_xor(sw, off, 16);
        a0 += __shfl_xor(a0, off, 16);
        a1 += __shfl_xor(a1, off, 16);
    }
    if (l16 == 0) {
        float z0 = a0 / sw + b2[0];
        float z1 = a1 / sw + b2[1];
        float mz = fmaxf(z0, z1);
        float lse = mz + logf(__expf(z0 - mz) + __expf(z1 - mz));
        out[wid * NCLS + 0] = z0 - lse;
        out[wid * NCLS + 1] = z1 - lse;
    }
}

// ---------------- launch ----------------

extern "C" void kernel_launch(void* const* d_in, const int* in_sizes, int n_in,
                              void* d_out, int out_size, void* d_ws, size_t ws_size,
                              hipStream_t stream) {
    const float* x   = (const float*)d_in[0];
    const int*   ei  = (const int*)d_in[1];
    const float* W1  = (const float*)d_in[2];
    const float* as1 = (const float*)d_in[3];
    const float* ad1 = (const float*)d_in[4];
    const float* b1  = (const float*)d_in[5];
    const float* W2  = (const float*)d_in[6];
    const float* as2 = (const float*)d_in[7];
    const float* ad2 = (const float*)d_in[8];
    const float* b2  = (const float*)d_in[9];
    float* out = (float*)d_out;

    const int n = in_sizes[0] / FIN;     // 50000
    const int e = in_sizes[1] / 2;       // 1600000
    const int tot = e + n;               // edges incl. self-loops

    char* ws = (char*)d_ws;
    size_t off = 0;
    auto alloc = [&](size_t bytes) -> void* {
        void* p = ws + off;
        off += (bytes + 255) & ~(size_t)255;
        return p;
    };
    __hip_bfloat16* h1b = (__hip_bfloat16*)alloc((size_t)n * HC * 2);
    int* pairs   = (int*)alloc((size_t)NBKT * CAP * 4);     // 8 MB, fixed slots
    int* csr     = (int*)alloc((size_t)NBKT * CAP * 4);     // 8 MB, padded layout
    float* es1   = (float*)alloc((size_t)n * NHEAD * 4);
    float* ed1   = (float*)alloc((size_t)n * NHEAD * 4);
    float4* node2 = (float4*)alloc((size_t)n * 16);
    int* rowptr  = (int*)alloc((size_t)n * 4);
    int* degv    = (int*)alloc((size_t)n * 4);
    int* bcur    = (int*)alloc(NBKT * 4);

    const int nbin = (tot + BCHUNK - 1) / BCHUNK;   // 403

    // CSR build: zero cursors, then single pass binning + per-bucket CSR
    hipMemsetAsync(bcur, 0, NBKT * 4, stream);
    k_binwrite<<<nbin, 256, 0, stream>>>(ei, bcur, pairs, e, tot);
    k_bucket_csr<<<NBKT, 256, 0, stream>>>(pairs, bcur, rowptr, degv, csr, n);

    // Layer 1 (+ fused layer-2 linear in agg1 epilogue)
    k_h1<<<1024, 256, 0, stream>>>(x, W1, as1, ad1, h1b, es1, ed1, n);
    k_agg1<<<(n * 64 + 255) / 256, 256, 0, stream>>>(h1b, es1, ed1, rowptr, degv, csr,
                                                     b1, W2, as2, ad2, node2, n);

    // Layer 2 aggregation
    k_agg2<<<(n * 16 + 255) / 256, 256, 0, stream>>>(node2, rowptr, degv, csr, b2, out, n);
}

// Round 7
// 131.852 us; speedup vs baseline: 3.1154x; 1.0161x over previous
//
#include <hip/hip_runtime.h>
#include <hip/hip_bf16.h>
#include <math.h>

#define NN 50000
#define FIN 48
#define HC 64   // 8 heads x 8 ch
#define NHEAD 8
#define NCH 8
#define NCLS 2
#define NEG 0.2f
#define LOG2E 1.44269504f

#define NPB 196                        // nodes per bucket
#define NBKT ((NN + NPB - 1) / NPB)    // 256 buckets
#define CAP 8192                       // fixed slot capacity per bucket (E[fill]=6450, +21 sigma)
#define BCHUNK 4096                    // edges per binning workgroup

// ---------------- CSR build: single-pass bucket sort into fixed-capacity slots ----------------

// one-pass WG-local counting sort: first LDS atomic gives local pos; stash in regs
__global__ void k_binwrite(const int* __restrict__ ei, int* __restrict__ bcur,
                           int* __restrict__ pairs, int e, int tot) {
    __shared__ int hist[NBKT];
    __shared__ int gbase[NBKT];
    int t = threadIdx.x;
    hist[t] = 0;
    __syncthreads();
    int base = blockIdx.x * BCHUNK;
    int end = min(base + BCHUNK, tot);
    int pk[16];   // payload (dloc<<16 | src)
    int bp[16];   // (bucket<<16 | local pos)
    #pragma unroll
    for (int k = 0; k < 16; ++k) {
        int i = base + t + k * 256;
        if (i < end) {
            int s, d;
            if (i < e) { s = ei[i]; d = ei[e + i]; }
            else       { s = d = i - e; }
            int b = d / NPB;
            int p = atomicAdd(&hist[b], 1);
            pk[k] = ((d - b * NPB) << 16) | s;
            bp[k] = (b << 16) | p;
        }
    }
    __syncthreads();
    int h = hist[t];
    gbase[t] = h ? atomicAdd(&bcur[t], h) : 0;
    __syncthreads();
    #pragma unroll
    for (int k = 0; k < 16; ++k) {
        int i = base + t + k * 256;
        if (i < end) {
            int b = bp[k] >> 16;
            int p = gbase[b] + (bp[k] & 0xFFFF);
            if (p < CAP) pairs[b * CAP + p] = pk[k];
        }
    }
}

// one WG per bucket: LDS degree hist -> scan -> rowptr/deg + csr scatter (L2-local)
__global__ void k_bucket_csr(const int* __restrict__ pairs, const int* __restrict__ bcur,
                             int* __restrict__ rowptr, int* __restrict__ degv,
                             int* __restrict__ csr, int n) {
    __shared__ int deg[256];
    __shared__ int cur[256];
    int b = blockIdx.x, t = threadIdx.x;
    int lo = b * NPB;
    int nn = min(NPB, n - lo);
    int base = b * CAP;
    int cnt = min(bcur[b], CAP);
    deg[t] = 0;
    __syncthreads();
    for (int i = t; i < cnt; i += 256) {
        atomicAdd(&deg[pairs[base + i] >> 16], 1);
    }
    __syncthreads();
    int v = deg[t];
    for (int off = 1; off < 256; off <<= 1) {
        int y = (t >= off) ? deg[t - off] : 0;
        __syncthreads();
        deg[t] += y;
        __syncthreads();
    }
    int excl = deg[t] - v;     // exclusive scan
    if (t < nn) { rowptr[lo + t] = base + excl; degv[lo + t] = v; }
    cur[t] = excl;
    __syncthreads();
    for (int i = t; i < cnt; i += 256) {
        int p = pairs[base + i];
        int pos = atomicAdd(&cur[p >> 16], 1);
        csr[base + pos] = p & 0xFFFF;
    }
}

// ---------------- Layer 1: h1 = x @ W1 (bf16 out) ; e_src/e_dst (pre-scaled by 1/ln2) ----------------

__global__ void k_h1(const float* __restrict__ x, const float* __restrict__ W1,
                     const float* __restrict__ as1, const float* __restrict__ ad1,
                     __hip_bfloat16* __restrict__ h1b, float* __restrict__ es1,
                     float* __restrict__ ed1, int n) {
    __shared__ float Wl[FIN * HC];
    __shared__ float xs[4][FIN];
    __shared__ float hr[4][HC];
    int tid = threadIdx.x;
    for (int i = tid; i < FIN * HC; i += 256) Wl[i] = W1[i];
    int ngroups = (n + 3) >> 2;
    int nl = tid >> 6, j = tid & 63;
    for (int g = blockIdx.x; g < ngroups; g += gridDim.x) {
        int nb = g * 4;
        __syncthreads();                 // protect xs/hr from previous iteration
        for (int i = tid; i < 4 * FIN; i += 256) {
            int l = i / FIN, k = i % FIN;
            int nd = nb + l;
            xs[l][k] = (nd < n) ? x[nd * FIN + k] : 0.f;
        }
        __syncthreads();
        float acc = 0.f;
        #pragma unroll
        for (int k = 0; k < FIN; ++k) acc += xs[nl][k] * Wl[k * HC + j];
        int nd = nb + nl;
        if (nd < n) h1b[nd * HC + j] = __float2bfloat16(acc);
        hr[nl][j] = acc;
        __syncthreads();
        if (j < 16 && nd < n) {
            int hh = j & 7;
            const float* av = (j < 8) ? as1 : ad1;
            float ev = 0.f;
            #pragma unroll
            for (int c = 0; c < NCH; ++c) ev += hr[nl][hh * NCH + c] * av[hh * NCH + c];
            ev *= LOG2E;   // pre-scale so agg uses raw exp2
            if (j < 8) es1[nd * NHEAD + hh] = ev;
            else       ed1[nd * NHEAD + hh] = ev;
        }
    }
}

// ---------------- Layer 1 aggregation + fused layer-2 linear ----------------
// wave per dst node; weight phase: lane (hw,j) computes weight of (edge j, head hw) once.
// accum phase: 4 edges x 16 lanes, each lane owns 4 channels (uint2 = 4 bf16 per load).

__global__ void k_agg1(const __hip_bfloat16* __restrict__ h1b, const float* __restrict__ es1,
                       const float* __restrict__ ed1, const int* __restrict__ rowptr,
                       const int* __restrict__ degv, const int* __restrict__ csr,
                       const float* __restrict__ b1,
                       const float* __restrict__ W2, const float* __restrict__ as2,
                       const float* __restrict__ ad2, float4* __restrict__ node2, int n) {
    int wid = (blockIdx.x * blockDim.x + threadIdx.x) >> 6;
    if (wid >= n) return;
    int lane = threadIdx.x & 63;
    int j  = lane & 7;                       // weight: edge slot
    int hw = lane >> 3;                      // weight: head
    int e4 = lane >> 4;                      // accum: edge sub-slot (0..3)
    int r  = lane & 15;
    int ha = r >> 1;                         // accum: head
    int ch0 = (ha << 3) + ((r & 1) << 2);    // first of this lane's 4 channels
    int wbase = (ha << 3) + e4;              // lane holding w for (slot e4, head ha)
    int start = rowptr[wid];
    int cnt = degv[wid];
    float edv = ed1[wid * NHEAD + hw];
    float sumw = 0.f;
    float a0 = 0.f, a1 = 0.f, a2 = 0.f, a3 = 0.f;
    int i = 0;
    for (; i + 8 <= cnt; i += 8) {           // full batches: no validity checks
        int sl = csr[start + i + j];
        float ev = es1[sl * NHEAD + hw] + edv;
        ev = fmaxf(ev, NEG * ev);            // leaky_relu (logits pre-scaled by 1/ln2)
        float w = exp2f(ev);
        sumw += w;
        #pragma unroll
        for (int it = 0; it < 2; ++it) {
            int su   = __shfl(sl, (it << 2) + e4, 64);
            float wj = __shfl(w, wbase + (it << 2), 64);
            uint2 v = *(const uint2*)(h1b + su * HC + ch0);
            float f0 = __uint_as_float(v.x << 16);
            float f1 = __uint_as_float(v.x & 0xffff0000u);
            float f2 = __uint_as_float(v.y << 16);
            float f3 = __uint_as_float(v.y & 0xffff0000u);
            a0 += wj * f0; a1 += wj * f1; a2 += wj * f2; a3 += wj * f3;
        }
    }
    if (i < cnt) {                            // tail batch (peeled)
        int last = start + cnt - 1;
        int idx = start + i + j;
        int sl = csr[idx > last ? last : idx];
        float ev = es1[sl * NHEAD + hw] + edv;
        ev = fmaxf(ev, NEG * ev);
        float w = (i + j < cnt) ? exp2f(ev) : 0.f;
        sumw += w;
        #pragma unroll
        for (int it = 0; it < 2; ++it) {
            int su   = __shfl(sl, (it << 2) + e4, 64);
            float wj = __shfl(w, wbase + (it << 2), 64);
            uint2 v = *(const uint2*)(h1b + su * HC + ch0);
            float f0 = __uint_as_float(v.x << 16);
            float f1 = __uint_as_float(v.x & 0xffff0000u);
            float f2 = __uint_as_float(v.y << 16);
            float f3 = __uint_as_float(v.y & 0xffff0000u);
            a0 += wj * f0; a1 += wj * f1; a2 += wj * f2; a3 += wj * f3;
        }
    }
    // denominator: reduce edge-slot partials within the head's 8-lane group
    sumw += __shfl_xor(sumw, 1, 64);
    sumw += __shfl_xor(sumw, 2, 64);
    sumw += __shfl_xor(sumw, 4, 64);
    // accumulator: sum the 4 edge sub-groups (lanes with same r)
    a0 += __shfl_xor(a0, 16, 64); a0 += __shfl_xor(a0, 32, 64);
    a1 += __shfl_xor(a1, 16, 64); a1 += __shfl_xor(a1, 32, 64);
    a2 += __shfl_xor(a2, 16, 64); a2 += __shfl_xor(a2, 32, 64);
    a3 += __shfl_xor(a3, 16, 64); a3 += __shfl_xor(a3, 32, 64);
    float sden = __shfl(sumw, ha << 3, 64);   // denominator of head ha
    float4 bv = *(const float4*)(b1 + ch0);
    float o0 = a0 / sden + bv.x;
    float o1 = a1 / sden + bv.y;
    float o2 = a2 / sden + bv.z;
    float o3 = a3 / sden + bv.w;
    o0 = o0 > 0.f ? o0 : expm1f(o0);          // fused bias + ELU
    o1 = o1 > 0.f ? o1 : expm1f(o1);
    o2 = o2 > 0.f ? o2 : expm1f(o2);
    o3 = o3 > 0.f ? o3 : expm1f(o3);
    // fused layer-2 linear: rows ch0..ch0+3 of W2 [HC][NCLS]
    float4 w01 = *(const float4*)(W2 + ch0 * 2);
    float4 w23 = *(const float4*)(W2 + ch0 * 2 + 4);
    float p0 = o0 * w01.x + o1 * w01.z + o2 * w23.x + o3 * w23.z;
    float p1 = o0 * w01.y + o1 * w01.w + o2 * w23.y + o3 * w23.w;
    #pragma unroll
    for (int off = 8; off > 0; off >>= 1) {
        p0 += __shfl_xor(p0, off, 64);
        p1 += __shfl_xor(p1, off, 64);
    }
    if (lane == 0) {
        float es2v = (p0 * as2[0] + p1 * as2[1]) * LOG2E;
        float ed2v = (p0 * ad2[0] + p1 * ad2[1]) * LOG2E;
        node2[wid] = make_float4(es2v, p0, p1, ed2v);
    }
}

// ---------------- Layer 2 aggregation + bias + log_softmax ----------------
// 16-lane segment per node (avg deg 33 -> ~2 iters), 4 nodes per wave

__global__ void k_agg2(const float4* __restrict__ node2, const int* __restrict__ rowptr,
                       const int* __restrict__ degv, const int* __restrict__ csr,
                       const float* __restrict__ b2, float* __restrict__ out, int n) {
    int lane = threadIdx.x & 63;
    int wid = ((blockIdx.x * blockDim.x + threadIdx.x) >> 6) * 4 + (lane >> 4);
    if (wid >= n) return;
    int l16 = lane & 15;
    int start = rowptr[wid];
    int cnt = degv[wid];
    float edv = ((const float*)node2)[wid * 4 + 3];
    float sw = 0.f, a0 = 0.f, a1 = 0.f;
    for (int i = l16; i < cnt; i += 16) {
        int s = csr[start + i];
        float4 t = node2[s];
        float val = t.x + edv;
        val = fmaxf(val, NEG * val);
        float w = exp2f(val);
        sw += w;
        a0 += w * t.y;
        a1 += w * t.z;
    }
    #pragma unroll
    for (int off = 8; off > 0; off >>= 1) {
        sw += __shfl_xor(sw, off, 16);
        a0 += __shfl_xor(a0, off, 16);
        a1 += __shfl_xor(a1, off, 16);
    }
    if (l16 == 0) {
        float z0 = a0 / sw + b2[0];
        float z1 = a1 / sw + b2[1];
        float mz = fmaxf(z0, z1);
        float lse = mz + logf(__expf(z0 - mz) + __expf(z1 - mz));
        out[wid * NCLS + 0] = z0 - lse;
        out[wid * NCLS + 1] = z1 - lse;
    }
}

// ---------------- launch ----------------

extern "C" void kernel_launch(void* const* d_in, const int* in_sizes, int n_in,
                              void* d_out, int out_size, void* d_ws, size_t ws_size,
                              hipStream_t stream) {
    const float* x   = (const float*)d_in[0];
    const int*   ei  = (const int*)d_in[1];
    const float* W1  = (const float*)d_in[2];
    const float* as1 = (const float*)d_in[3];
    const float* ad1 = (const float*)d_in[4];
    const float* b1  = (const float*)d_in[5];
    const float* W2  = (const float*)d_in[6];
    const float* as2 = (const float*)d_in[7];
    const float* ad2 = (const float*)d_in[8];
    const float* b2  = (const float*)d_in[9];
    float* out = (float*)d_out;

    const int n = in_sizes[0] / FIN;     // 50000
    const int e = in_sizes[1] / 2;       // 1600000
    const int tot = e + n;               // edges incl. self-loops

    char* ws = (char*)d_ws;
    size_t off = 0;
    auto alloc = [&](size_t bytes) -> void* {
        void* p = ws + off;
        off += (bytes + 255) & ~(size_t)255;
        return p;
    };
    __hip_bfloat16* h1b = (__hip_bfloat16*)alloc((size_t)n * HC * 2);
    int* pairs   = (int*)alloc((size_t)NBKT * CAP * 4);     // 8 MB, fixed slots
    int* csr     = (int*)alloc((size_t)NBKT * CAP * 4);     // 8 MB, padded layout
    float* es1   = (float*)alloc((size_t)n * NHEAD * 4);
    float* ed1   = (float*)alloc((size_t)n * NHEAD * 4);
    float4* node2 = (float4*)alloc((size_t)n * 16);
    int* rowptr  = (int*)alloc((size_t)n * 4);
    int* degv    = (int*)alloc((size_t)n * 4);
    int* bcur    = (int*)alloc(NBKT * 4);

    const int nbin = (tot + BCHUNK - 1) / BCHUNK;   // 403

    // CSR build: zero cursors, then single pass binning + per-bucket CSR
    hipMemsetAsync(bcur, 0, NBKT * 4, stream);
    k_binwrite<<<nbin, 256, 0, stream>>>(ei, bcur, pairs, e, tot);
    k_bucket_csr<<<NBKT, 256, 0, stream>>>(pairs, bcur, rowptr, degv, csr, n);

    // Layer 1 (+ fused layer-2 linear in agg1 epilogue)
    k_h1<<<1024, 256, 0, stream>>>(x, W1, as1, ad1, h1b, es1, ed1, n);
    k_agg1<<<(n * 64 + 255) / 256, 256, 0, stream>>>(h1b, es1, ed1, rowptr, degv, csr,
                                                     b1, W2, as2, ad2, node2, n);

    // Layer 2 aggregation
    k_agg2<<<(n * 16 + 255) / 256, 256, 0, stream>>>(node2, rowptr, degv, csr, b2, out, n);
}

// Round 8
// 130.172 us; speedup vs baseline: 3.1556x; 1.0129x over previous
//
#include <hip/hip_runtime.h>
#include <hip/hip_bf16.h>
#include <math.h>

#define NN 50000
#define FIN 48
#define HC 64   // 8 heads x 8 ch
#define NHEAD 8
#define NCH 8
#define NCLS 2
#define NEG 0.2f
#define LOG2E 1.44269504f

#define NPB 98                         // nodes per bucket
#define NBKT 512                       // buckets (NPB*NBKT >= NN)
#define CAP 4096                       // fixed slot capacity (E[fill]=3225, +15 sigma)
#define BCHUNK 4096                    // edges per binning workgroup

// ---------------- CSR build: single-pass bucket sort into fixed-capacity slots ----------------

__global__ void k_binwrite(const int* __restrict__ ei, int* __restrict__ bcur,
                           int* __restrict__ pairs, int e, int tot) {
    __shared__ int hist[NBKT];
    __shared__ int gbase[NBKT];
    int t = threadIdx.x;
    hist[t] = 0; hist[t + 256] = 0;
    __syncthreads();
    int base = blockIdx.x * BCHUNK;
    int end = min(base + BCHUNK, tot);
    int pk[16];   // payload (dloc<<16 | src)
    int bp[16];   // (bucket<<16 | local pos)
    #pragma unroll
    for (int k = 0; k < 16; ++k) {
        int i = base + t + k * 256;
        if (i < end) {
            int s, d;
            if (i < e) { s = ei[i]; d = ei[e + i]; }
            else       { s = d = i - e; }
            int b = d / NPB;
            int p = atomicAdd(&hist[b], 1);
            pk[k] = ((d - b * NPB) << 16) | s;
            bp[k] = (b << 16) | p;
        }
    }
    __syncthreads();
    for (int u = t; u < NBKT; u += 256) {
        int h = hist[u];
        gbase[u] = h ? atomicAdd(&bcur[u], h) : 0;
    }
    __syncthreads();
    #pragma unroll
    for (int k = 0; k < 16; ++k) {
        int i = base + t + k * 256;
        if (i < end) {
            int b = bp[k] >> 16;
            int p = gbase[b] + (bp[k] & 0xFFFF);
            if (p < CAP) pairs[b * CAP + p] = pk[k];
        }
    }
}

// one WG per bucket: LDS degree hist -> scan -> rowptr/deg + csr scatter (L2-local)
__global__ void k_bucket_csr(const int* __restrict__ pairs, const int* __restrict__ bcur,
                             int* __restrict__ rowptr, int* __restrict__ degv,
                             int* __restrict__ csr, int n) {
    __shared__ int deg[256];
    __shared__ int cur[256];
    int b = blockIdx.x, t = threadIdx.x;
    int lo = b * NPB;
    int nn = min(NPB, n - lo);
    if (nn <= 0) return;
    int base = b * CAP;
    int cnt = min(bcur[b], CAP);
    deg[t] = 0;
    __syncthreads();
    for (int i = t; i < cnt; i += 256) {
        atomicAdd(&deg[pairs[base + i] >> 16], 1);
    }
    __syncthreads();
    int v = deg[t];
    for (int off = 1; off < 256; off <<= 1) {
        int y = (t >= off) ? deg[t - off] : 0;
        __syncthreads();
        deg[t] += y;
        __syncthreads();
    }
    int excl = deg[t] - v;     // exclusive scan
    if (t < nn) { rowptr[lo + t] = base + excl; degv[lo + t] = v; }
    cur[t] = excl;
    __syncthreads();
    for (int i = t; i < cnt; i += 256) {
        int p = pairs[base + i];
        int pos = atomicAdd(&cur[p >> 16], 1);
        csr[base + pos] = p & 0xFFFF;
    }
}

// ---------------- Layer 1: h1 = x @ W1 (bf16 out) ; e_src/e_dst (pre-scaled by 1/ln2) ----------------

__global__ void k_h1(const float* __restrict__ x, const float* __restrict__ W1,
                     const float* __restrict__ as1, const float* __restrict__ ad1,
                     __hip_bfloat16* __restrict__ h1b, float* __restrict__ es1,
                     float* __restrict__ ed1, int n) {
    __shared__ float Wl[FIN * HC];
    __shared__ float xs[4][FIN];
    __shared__ float hr[4][HC];
    int tid = threadIdx.x;
    for (int i = tid; i < FIN * HC; i += 256) Wl[i] = W1[i];
    int ngroups = (n + 3) >> 2;
    int nl = tid >> 6, j = tid & 63;
    for (int g = blockIdx.x; g < ngroups; g += gridDim.x) {
        int nb = g * 4;
        __syncthreads();                 // protect xs/hr from previous iteration
        for (int i = tid; i < 4 * FIN; i += 256) {
            int l = i / FIN, k = i % FIN;
            int nd = nb + l;
            xs[l][k] = (nd < n) ? x[nd * FIN + k] : 0.f;
        }
        __syncthreads();
        float acc = 0.f;
        #pragma unroll
        for (int k = 0; k < FIN; ++k) acc += xs[nl][k] * Wl[k * HC + j];
        int nd = nb + nl;
        if (nd < n) h1b[nd * HC + j] = __float2bfloat16(acc);
        hr[nl][j] = acc;
        __syncthreads();
        if (j < 16 && nd < n) {
            int hh = j & 7;
            const float* av = (j < 8) ? as1 : ad1;
            float ev = 0.f;
            #pragma unroll
            for (int c = 0; c < NCH; ++c) ev += hr[nl][hh * NCH + c] * av[hh * NCH + c];
            ev *= LOG2E;   // pre-scale so agg uses raw exp2
            if (j < 8) es1[nd * NHEAD + hh] = ev;
            else       ed1[nd * NHEAD + hh] = ev;
        }
    }
}

// ---------------- Layer 1 aggregation + fused layer-2 linear ----------------
// wave per dst node; software-pipelined: batch b+1 loads issue while batch b consumes.

__global__ void k_agg1(const __hip_bfloat16* __restrict__ h1b, const float* __restrict__ es1,
                       const float* __restrict__ ed1, const int* __restrict__ rowptr,
                       const int* __restrict__ degv, const int* __restrict__ csr,
                       const float* __restrict__ b1,
                       const float* __restrict__ W2, const float* __restrict__ as2,
                       const float* __restrict__ ad2, float4* __restrict__ node2, int n) {
    int wid = (blockIdx.x * blockDim.x + threadIdx.x) >> 6;
    if (wid >= n) return;
    int lane = threadIdx.x & 63;
    int j  = lane & 7;                       // weight: edge slot
    int hw = lane >> 3;                      // weight: head
    int e4 = lane >> 4;                      // accum: edge sub-slot (0..3)
    int r  = lane & 15;
    int ha = r >> 1;                         // accum: head
    int ch0 = (ha << 3) + ((r & 1) << 2);    // first of this lane's 4 channels
    int wbase = (ha << 3) + e4;              // lane holding w for (slot e4, head ha)
    int start = rowptr[wid];
    int cnt = degv[wid];
    float edv = ed1[wid * NHEAD + hw];
    float sumw = 0.f;
    float a0 = 0.f, a1 = 0.f, a2 = 0.f, a3 = 0.f;
    int nbatch = cnt >> 3;

    int sl; float ev; uint2 va, vb;
    if (nbatch > 0) {
        // prologue: load batch 0
        sl = __builtin_nontemporal_load(csr + start + j);
        ev = es1[sl * NHEAD + hw];
        int su0 = __shfl(sl, e4, 64);
        int su1 = __shfl(sl, 4 + e4, 64);
        va = *(const uint2*)(h1b + su0 * HC + ch0);
        vb = *(const uint2*)(h1b + su1 * HC + ch0);
        for (int b = 1; b < nbatch; ++b) {
            // issue batch b loads
            int sl_n = __builtin_nontemporal_load(csr + start + b * 8 + j);
            float ev_n = es1[sl_n * NHEAD + hw];
            int su0n = __shfl(sl_n, e4, 64);
            int su1n = __shfl(sl_n, 4 + e4, 64);
            uint2 va_n = *(const uint2*)(h1b + su0n * HC + ch0);
            uint2 vb_n = *(const uint2*)(h1b + su1n * HC + ch0);
            // consume batch b-1 from registers
            float t = ev + edv;
            t = fmaxf(t, NEG * t);
            float w = exp2f(t);
            sumw += w;
            float wj0 = __shfl(w, wbase, 64);
            float wj1 = __shfl(w, wbase + 4, 64);
            a0 += wj0 * __uint_as_float(va.x << 16);
            a1 += wj0 * __uint_as_float(va.x & 0xffff0000u);
            a2 += wj0 * __uint_as_float(va.y << 16);
            a3 += wj0 * __uint_as_float(va.y & 0xffff0000u);
            a0 += wj1 * __uint_as_float(vb.x << 16);
            a1 += wj1 * __uint_as_float(vb.x & 0xffff0000u);
            a2 += wj1 * __uint_as_float(vb.y << 16);
            a3 += wj1 * __uint_as_float(vb.y & 0xffff0000u);
            sl = sl_n; ev = ev_n; va = va_n; vb = vb_n;
        }
        // epilogue: consume last full batch
        float t = ev + edv;
        t = fmaxf(t, NEG * t);
        float w = exp2f(t);
        sumw += w;
        float wj0 = __shfl(w, wbase, 64);
        float wj1 = __shfl(w, wbase + 4, 64);
        a0 += wj0 * __uint_as_float(va.x << 16);
        a1 += wj0 * __uint_as_float(va.x & 0xffff0000u);
        a2 += wj0 * __uint_as_float(va.y << 16);
        a3 += wj0 * __uint_as_float(va.y & 0xffff0000u);
        a0 += wj1 * __uint_as_float(vb.x << 16);
        a1 += wj1 * __uint_as_float(vb.x & 0xffff0000u);
        a2 += wj1 * __uint_as_float(vb.y << 16);
        a3 += wj1 * __uint_as_float(vb.y & 0xffff0000u);
    }
    int i = nbatch << 3;
    if (i < cnt) {                            // tail batch (peeled, clamped)
        int last = start + cnt - 1;
        int idx = start + i + j;
        int slt = csr[idx > last ? last : idx];
        float evt = es1[slt * NHEAD + hw] + edv;
        evt = fmaxf(evt, NEG * evt);
        float w = (i + j < cnt) ? exp2f(evt) : 0.f;
        sumw += w;
        #pragma unroll
        for (int it = 0; it < 2; ++it) {
            int su   = __shfl(slt, (it << 2) + e4, 64);
            float wj = __shfl(w, wbase + (it << 2), 64);
            uint2 v = *(const uint2*)(h1b + su * HC + ch0);
            a0 += wj * __uint_as_float(v.x << 16);
            a1 += wj * __uint_as_float(v.x & 0xffff0000u);
            a2 += wj * __uint_as_float(v.y << 16);
            a3 += wj * __uint_as_float(v.y & 0xffff0000u);
        }
    }
    // denominator: reduce edge-slot partials within the head's 8-lane group
    sumw += __shfl_xor(sumw, 1, 64);
    sumw += __shfl_xor(sumw, 2, 64);
    sumw += __shfl_xor(sumw, 4, 64);
    // accumulator: sum the 4 edge sub-groups (lanes with same r)
    a0 += __shfl_xor(a0, 16, 64); a0 += __shfl_xor(a0, 32, 64);
    a1 += __shfl_xor(a1, 16, 64); a1 += __shfl_xor(a1, 32, 64);
    a2 += __shfl_xor(a2, 16, 64); a2 += __shfl_xor(a2, 32, 64);
    a3 += __shfl_xor(a3, 16, 64); a3 += __shfl_xor(a3, 32, 64);
    float sden = __shfl(sumw, ha << 3, 64);   // denominator of head ha
    float4 bv = *(const float4*)(b1 + ch0);
    float o0 = a0 / sden + bv.x;
    float o1 = a1 / sden + bv.y;
    float o2 = a2 / sden + bv.z;
    float o3 = a3 / sden + bv.w;
    o0 = o0 > 0.f ? o0 : expm1f(o0);          // fused bias + ELU
    o1 = o1 > 0.f ? o1 : expm1f(o1);
    o2 = o2 > 0.f ? o2 : expm1f(o2);
    o3 = o3 > 0.f ? o3 : expm1f(o3);
    // fused layer-2 linear: rows ch0..ch0+3 of W2 [HC][NCLS]
    float4 w01 = *(const float4*)(W2 + ch0 * 2);
    float4 w23 = *(const float4*)(W2 + ch0 * 2 + 4);
    float p0 = o0 * w01.x + o1 * w01.z + o2 * w23.x + o3 * w23.z;
    float p1 = o0 * w01.y + o1 * w01.w + o2 * w23.y + o3 * w23.w;
    #pragma unroll
    for (int off = 8; off > 0; off >>= 1) {
        p0 += __shfl_xor(p0, off, 64);
        p1 += __shfl_xor(p1, off, 64);
    }
    if (lane == 0) {
        float es2v = (p0 * as2[0] + p1 * as2[1]) * LOG2E;
        float ed2v = (p0 * ad2[0] + p1 * ad2[1]) * LOG2E;
        node2[wid] = make_float4(es2v, p0, p1, ed2v);
    }
}

// ---------------- Layer 2 aggregation + bias + log_softmax ----------------
// 16-lane segment per node (avg deg 33 -> ~2 iters), 4 nodes per wave

__global__ void k_agg2(const float4* __restrict__ node2, const int* __restrict__ rowptr,
                       const int* __restrict__ degv, const int* __restrict__ csr,
                       const float* __restrict__ b2, float* __restrict__ out, int n) {
    int lane = threadIdx.x & 63;
    int wid = ((blockIdx.x * blockDim.x + threadIdx.x) >> 6) * 4 + (lane >> 4);
    if (wid >= n) return;
    int l16 = lane & 15;
    int start = rowptr[wid];
    int cnt = degv[wid];
    float edv = ((const float*)node2)[wid * 4 + 3];
    float sw = 0.f, a0 = 0.f, a1 = 0.f;
    for (int i = l16; i < cnt; i += 16) {
        int s = __builtin_nontemporal_load(csr + start + i);
        float4 t = node2[s];
        float val = t.x + edv;
        val = fmaxf(val, NEG * val);
        float w = exp2f(val);
        sw += w;
        a0 += w * t.y;
        a1 += w * t.z;
    }
    #pragma unroll
    for (int off = 8; off > 0; off >>= 1) {
        sw += __shfl_xor(sw, off, 16);
        a0 += __shfl_xor(a0, off, 16);
        a1 += __shfl_xor(a1, off, 16);
    }
    if (l16 == 0) {
        float z0 = a0 / sw + b2[0];
        float z1 = a1 / sw + b2[1];
        float mz = fmaxf(z0, z1);
        float lse = mz + logf(__expf(z0 - mz) + __expf(z1 - mz));
        out[wid * NCLS + 0] = z0 - lse;
        out[wid * NCLS + 1] = z1 - lse;
    }
}

// ---------------- launch ----------------

extern "C" void kernel_launch(void* const* d_in, const int* in_sizes, int n_in,
                              void* d_out, int out_size, void* d_ws, size_t ws_size,
                              hipStream_t stream) {
    const float* x   = (const float*)d_in[0];
    const int*   ei  = (const int*)d_in[1];
    const float* W1  = (const float*)d_in[2];
    const float* as1 = (const float*)d_in[3];
    const float* ad1 = (const float*)d_in[4];
    const float* b1  = (const float*)d_in[5];
    const float* W2  = (const float*)d_in[6];
    const float* as2 = (const float*)d_in[7];
    const float* ad2 = (const float*)d_in[8];
    const float* b2  = (const float*)d_in[9];
    float* out = (float*)d_out;

    const int n = in_sizes[0] / FIN;     // 50000
    const int e = in_sizes[1] / 2;       // 1600000
    const int tot = e + n;               // edges incl. self-loops

    char* ws = (char*)d_ws;
    size_t off = 0;
    auto alloc = [&](size_t bytes) -> void* {
        void* p = ws + off;
        off += (bytes + 255) & ~(size_t)255;
        return p;
    };
    __hip_bfloat16* h1b = (__hip_bfloat16*)alloc((size_t)n * HC * 2);
    int* pairs   = (int*)alloc((size_t)NBKT * CAP * 4);     // 8 MB, fixed slots
    int* csr     = (int*)alloc((size_t)NBKT * CAP * 4);     // 8 MB, padded layout
    float* es1   = (float*)alloc((size_t)n * NHEAD * 4);
    float* ed1   = (float*)alloc((size_t)n * NHEAD * 4);
    float4* node2 = (float4*)alloc((size_t)n * 16);
    int* rowptr  = (int*)alloc((size_t)n * 4);
    int* degv    = (int*)alloc((size_t)n * 4);
    int* bcur    = (int*)alloc(NBKT * 4);

    const int nbin = (tot + BCHUNK - 1) / BCHUNK;   // 403

    // CSR build: zero cursors, then single pass binning + per-bucket CSR
    hipMemsetAsync(bcur, 0, NBKT * 4, stream);
    k_binwrite<<<nbin, 256, 0, stream>>>(ei, bcur, pairs, e, tot);
    k_bucket_csr<<<NBKT, 256, 0, stream>>>(pairs, bcur, rowptr, degv, csr, n);

    // Layer 1 (+ fused layer-2 linear in agg1 epilogue)
    k_h1<<<1024, 256, 0, stream>>>(x, W1, as1, ad1, h1b, es1, ed1, n);
    k_agg1<<<(n * 64 + 255) / 256, 256, 0, stream>>>(h1b, es1, ed1, rowptr, degv, csr,
                                                     b1, W2, as2, ad2, node2, n);

    // Layer 2 aggregation
    k_agg2<<<(n * 16 + 255) / 256, 256, 0, stream>>>(node2, rowptr, degv, csr, b2, out, n);
}

// Round 9
// 121.575 us; speedup vs baseline: 3.3787x; 1.0707x over previous
//
#include <hip/hip_runtime.h>
#include <hip/hip_bf16.h>
#include <math.h>

#define NN 50000
#define FIN 48
#define HC 64   // 8 heads x 8 ch
#define NHEAD 8
#define NCH 8
#define NCLS 2
#define NEG 0.2f
#define LOG2E 1.44269504f

#define NPB 98                         // nodes per bucket
#define NBKT 512                       // buckets (NPB*NBKT >= NN)
#define CAP 4096                       // fixed slot capacity (E[fill]=3225, +15 sigma)
#define BCHUNK 4096                    // edges per binning workgroup
#define NR 8                           // src ranges for intra-row radix (src>>13)
#define RSH 13

// ---------------- fused: edge binning (blocks 0..nbin-1)  ||  layer-1 GEMM (rest) ----------------

__global__ void k_bin_h1(const int* __restrict__ ei, int* __restrict__ bcur,
                         int* __restrict__ pairs, int e, int tot, int nbin,
                         const float* __restrict__ x, const float* __restrict__ W1,
                         const float* __restrict__ as1, const float* __restrict__ ad1,
                         __hip_bfloat16* __restrict__ h1b, float* __restrict__ es1,
                         float* __restrict__ ed1, int n) {
    __shared__ int hist[NBKT];
    __shared__ int gbase[NBKT];
    __shared__ float Wl[FIN * HC];
    __shared__ float xs[4][FIN];
    __shared__ float hr[4][HC];
    int t = threadIdx.x;
    if ((int)blockIdx.x < nbin) {
        // ---- binning: one-pass WG-local counting sort ----
        hist[t] = 0; hist[t + 256] = 0;
        __syncthreads();
        int base = blockIdx.x * BCHUNK;
        int end = min(base + BCHUNK, tot);
        int pk[16];   // payload (dloc<<16 | src)
        int bp[16];   // (bucket<<16 | local pos)
        #pragma unroll
        for (int k = 0; k < 16; ++k) {
            int i = base + t + k * 256;
            if (i < end) {
                int s, d;
                if (i < e) { s = ei[i]; d = ei[e + i]; }
                else       { s = d = i - e; }
                int b = d / NPB;
                int p = atomicAdd(&hist[b], 1);
                pk[k] = ((d - b * NPB) << 16) | s;
                bp[k] = (b << 16) | p;
            }
        }
        __syncthreads();
        for (int u = t; u < NBKT; u += 256) {
            int h = hist[u];
            gbase[u] = h ? atomicAdd(&bcur[u], h) : 0;
        }
        __syncthreads();
        #pragma unroll
        for (int k = 0; k < 16; ++k) {
            int i = base + t + k * 256;
            if (i < end) {
                int b = bp[k] >> 16;
                int p = gbase[b] + (bp[k] & 0xFFFF);
                if (p < CAP) pairs[b * CAP + p] = pk[k];
            }
        }
    } else {
        // ---- layer-1: h1 = x @ W1 (bf16) ; es/ed logits pre-scaled by 1/ln2 ----
        for (int i = t; i < FIN * HC; i += 256) Wl[i] = W1[i];
        int ngroups = (n + 3) >> 2;
        int nl = t >> 6, j = t & 63;
        for (int g = blockIdx.x - nbin; g < ngroups; g += gridDim.x - nbin) {
            int nb = g * 4;
            __syncthreads();
            for (int i = t; i < 4 * FIN; i += 256) {
                int l = i / FIN, k = i % FIN;
                int nd = nb + l;
                xs[l][k] = (nd < n) ? x[nd * FIN + k] : 0.f;
            }
            __syncthreads();
            float acc = 0.f;
            #pragma unroll
            for (int k = 0; k < FIN; ++k) acc += xs[nl][k] * Wl[k * HC + j];
            int nd = nb + nl;
            if (nd < n) h1b[nd * HC + j] = __float2bfloat16(acc);
            hr[nl][j] = acc;
            __syncthreads();
            if (j < 16 && nd < n) {
                int hh = j & 7;
                const float* av = (j < 8) ? as1 : ad1;
                float ev = 0.f;
                #pragma unroll
                for (int c = 0; c < NCH; ++c) ev += hr[nl][hh * NCH + c] * av[hh * NCH + c];
                ev *= LOG2E;
                if (j < 8) es1[nd * NHEAD + hh] = ev;
                else       ed1[nd * NHEAD + hh] = ev;
            }
        }
    }
}

// ---------------- per-bucket CSR with intra-row src-range radix ----------------
// key = (dloc<<3)|src_range; scan 98*8=784 counters; csr rows come out sorted by
// src range -> all waves gather from a sliding ~1MB window of h1b (L2-resident).

__global__ void k_bucket_csr(const int* __restrict__ pairs, const int* __restrict__ bcur,
                             int* __restrict__ rowptr, int* __restrict__ degv,
                             int* __restrict__ csr, int n) {
    __shared__ int hist[1024];
    __shared__ int scanbuf[256];
    int b = blockIdx.x, t = threadIdx.x;
    int lo = b * NPB;
    int nn = min(NPB, n - lo);
    if (nn <= 0) return;
    int base = b * CAP;
    int cnt = min(bcur[b], CAP);
    #pragma unroll
    for (int k = 0; k < 4; ++k) hist[t + k * 256] = 0;
    __syncthreads();
    for (int i = t; i < cnt; i += 256) {
        int p = pairs[base + i];
        int key = ((p >> 16) << 3) | ((p & 0xFFFF) >> RSH);
        atomicAdd(&hist[key], 1);
    }
    __syncthreads();
    // exclusive scan of hist[0..1024): 4 elems/thread + 256-wide Hillis-Steele
    int c0 = hist[t * 4], c1 = hist[t * 4 + 1], c2 = hist[t * 4 + 2], c3 = hist[t * 4 + 3];
    int s = c0 + c1 + c2 + c3;
    scanbuf[t] = s;
    __syncthreads();
    for (int off = 1; off < 256; off <<= 1) {
        int y = (t >= off) ? scanbuf[t - off] : 0;
        __syncthreads();
        scanbuf[t] += y;
        __syncthreads();
    }
    int excl = scanbuf[t] - s;
    hist[t * 4]     = excl;
    hist[t * 4 + 1] = excl + c0;
    hist[t * 4 + 2] = excl + c0 + c1;
    hist[t * 4 + 3] = excl + c0 + c1 + c2;
    __syncthreads();
    if (t < nn) {
        int r0 = hist[t << 3];
        rowptr[lo + t] = base + r0;
        degv[lo + t] = hist[(t + 1) << 3] - r0;   // hist[784] == cnt (padding scanned)
    }
    __syncthreads();
    for (int i = t; i < cnt; i += 256) {
        int p = pairs[base + i];
        int key = ((p >> 16) << 3) | ((p & 0xFFFF) >> RSH);
        int pos = atomicAdd(&hist[key], 1);
        csr[base + pos] = p & 0xFFFF;
    }
}

// ---------------- Layer 1 aggregation + fused layer-2 linear ----------------
// wave per dst node; software-pipelined; weight lane (hw,j), accum lane 4ch x 16.

__global__ void k_agg1(const __hip_bfloat16* __restrict__ h1b, const float* __restrict__ es1,
                       const float* __restrict__ ed1, const int* __restrict__ rowptr,
                       const int* __restrict__ degv, const int* __restrict__ csr,
                       const float* __restrict__ b1,
                       const float* __restrict__ W2, const float* __restrict__ as2,
                       const float* __restrict__ ad2, float4* __restrict__ node2, int n) {
    int wid = (blockIdx.x * blockDim.x + threadIdx.x) >> 6;
    if (wid >= n) return;
    int lane = threadIdx.x & 63;
    int j  = lane & 7;                       // weight: edge slot
    int hw = lane >> 3;                      // weight: head
    int e4 = lane >> 4;                      // accum: edge sub-slot (0..3)
    int r  = lane & 15;
    int ha = r >> 1;                         // accum: head
    int ch0 = (ha << 3) + ((r & 1) << 2);    // first of this lane's 4 channels
    int wbase = (ha << 3) + e4;              // lane holding w for (slot e4, head ha)
    int start = rowptr[wid];
    int cnt = degv[wid];
    float edv = ed1[wid * NHEAD + hw];
    float sumw = 0.f;
    float a0 = 0.f, a1 = 0.f, a2 = 0.f, a3 = 0.f;
    int nbatch = cnt >> 3;

    int sl; float ev; uint2 va, vb;
    if (nbatch > 0) {
        sl = __builtin_nontemporal_load(csr + start + j);
        ev = es1[sl * NHEAD + hw];
        int su0 = __shfl(sl, e4, 64);
        int su1 = __shfl(sl, 4 + e4, 64);
        va = *(const uint2*)(h1b + su0 * HC + ch0);
        vb = *(const uint2*)(h1b + su1 * HC + ch0);
        for (int b = 1; b < nbatch; ++b) {
            int sl_n = __builtin_nontemporal_load(csr + start + b * 8 + j);
            float ev_n = es1[sl_n * NHEAD + hw];
            int su0n = __shfl(sl_n, e4, 64);
            int su1n = __shfl(sl_n, 4 + e4, 64);
            uint2 va_n = *(const uint2*)(h1b + su0n * HC + ch0);
            uint2 vb_n = *(const uint2*)(h1b + su1n * HC + ch0);
            float tt = ev + edv;
            tt = fmaxf(tt, NEG * tt);
            float w = exp2f(tt);
            sumw += w;
            float wj0 = __shfl(w, wbase, 64);
            float wj1 = __shfl(w, wbase + 4, 64);
            a0 += wj0 * __uint_as_float(va.x << 16);
            a1 += wj0 * __uint_as_float(va.x & 0xffff0000u);
            a2 += wj0 * __uint_as_float(va.y << 16);
            a3 += wj0 * __uint_as_float(va.y & 0xffff0000u);
            a0 += wj1 * __uint_as_float(vb.x << 16);
            a1 += wj1 * __uint_as_float(vb.x & 0xffff0000u);
            a2 += wj1 * __uint_as_float(vb.y << 16);
            a3 += wj1 * __uint_as_float(vb.y & 0xffff0000u);
            sl = sl_n; ev = ev_n; va = va_n; vb = vb_n;
        }
        float tt = ev + edv;
        tt = fmaxf(tt, NEG * tt);
        float w = exp2f(tt);
        sumw += w;
        float wj0 = __shfl(w, wbase, 64);
        float wj1 = __shfl(w, wbase + 4, 64);
        a0 += wj0 * __uint_as_float(va.x << 16);
        a1 += wj0 * __uint_as_float(va.x & 0xffff0000u);
        a2 += wj0 * __uint_as_float(va.y << 16);
        a3 += wj0 * __uint_as_float(va.y & 0xffff0000u);
        a0 += wj1 * __uint_as_float(vb.x << 16);
        a1 += wj1 * __uint_as_float(vb.x & 0xffff0000u);
        a2 += wj1 * __uint_as_float(vb.y << 16);
        a3 += wj1 * __uint_as_float(vb.y & 0xffff0000u);
    }
    int i = nbatch << 3;
    if (i < cnt) {                            // tail batch (peeled, clamped)
        int last = start + cnt - 1;
        int idx = start + i + j;
        int slt = csr[idx > last ? last : idx];
        float evt = es1[slt * NHEAD + hw] + edv;
        evt = fmaxf(evt, NEG * evt);
        float w = (i + j < cnt) ? exp2f(evt) : 0.f;
        sumw += w;
        #pragma unroll
        for (int it = 0; it < 2; ++it) {
            int su   = __shfl(slt, (it << 2) + e4, 64);
            float wj = __shfl(w, wbase + (it << 2), 64);
            uint2 v = *(const uint2*)(h1b + su * HC + ch0);
            a0 += wj * __uint_as_float(v.x << 16);
            a1 += wj * __uint_as_float(v.x & 0xffff0000u);
            a2 += wj * __uint_as_float(v.y << 16);
            a3 += wj * __uint_as_float(v.y & 0xffff0000u);
        }
    }
    sumw += __shfl_xor(sumw, 1, 64);
    sumw += __shfl_xor(sumw, 2, 64);
    sumw += __shfl_xor(sumw, 4, 64);
    a0 += __shfl_xor(a0, 16, 64); a0 += __shfl_xor(a0, 32, 64);
    a1 += __shfl_xor(a1, 16, 64); a1 += __shfl_xor(a1, 32, 64);
    a2 += __shfl_xor(a2, 16, 64); a2 += __shfl_xor(a2, 32, 64);
    a3 += __shfl_xor(a3, 16, 64); a3 += __shfl_xor(a3, 32, 64);
    float sden = __shfl(sumw, ha << 3, 64);
    float4 bv = *(const float4*)(b1 + ch0);
    float o0 = a0 / sden + bv.x;
    float o1 = a1 / sden + bv.y;
    float o2 = a2 / sden + bv.z;
    float o3 = a3 / sden + bv.w;
    o0 = o0 > 0.f ? o0 : expm1f(o0);
    o1 = o1 > 0.f ? o1 : expm1f(o1);
    o2 = o2 > 0.f ? o2 : expm1f(o2);
    o3 = o3 > 0.f ? o3 : expm1f(o3);
    float4 w01 = *(const float4*)(W2 + ch0 * 2);
    float4 w23 = *(const float4*)(W2 + ch0 * 2 + 4);
    float p0 = o0 * w01.x + o1 * w01.z + o2 * w23.x + o3 * w23.z;
    float p1 = o0 * w01.y + o1 * w01.w + o2 * w23.y + o3 * w23.w;
    #pragma unroll
    for (int off = 8; off > 0; off >>= 1) {
        p0 += __shfl_xor(p0, off, 64);
        p1 += __shfl_xor(p1, off, 64);
    }
    if (lane == 0) {
        float es2v = (p0 * as2[0] + p1 * as2[1]) * LOG2E;
        float ed2v = (p0 * ad2[0] + p1 * ad2[1]) * LOG2E;
        node2[wid] = make_float4(es2v, p0, p1, ed2v);
    }
}

// ---------------- Layer 2 aggregation + bias + log_softmax ----------------

__global__ void k_agg2(const float4* __restrict__ node2, const int* __restrict__ rowptr,
                       const int* __restrict__ degv, const int* __restrict__ csr,
                       const float* __restrict__ b2, float* __restrict__ out, int n) {
    int lane = threadIdx.x & 63;
    int wid = ((blockIdx.x * blockDim.x + threadIdx.x) >> 6) * 4 + (lane >> 4);
    if (wid >= n) return;
    int l16 = lane & 15;
    int start = rowptr[wid];
    int cnt = degv[wid];
    float edv = ((const float*)node2)[wid * 4 + 3];
    float sw = 0.f, a0 = 0.f, a1 = 0.f;
    for (int i = l16; i < cnt; i += 16) {
        int s = __builtin_nontemporal_load(csr + start + i);
        float4 t = node2[s];
        float val = t.x + edv;
        val = fmaxf(val, NEG * val);
        float w = exp2f(val);
        sw += w;
        a0 += w * t.y;
        a1 += w * t.z;
    }
    #pragma unroll
    for (int off = 8; off > 0; off >>= 1) {
        sw += __shfl_xor(sw, off, 16);
        a0 += __shfl_xor(a0, off, 16);
        a1 += __shfl_xor(a1, off, 16);
    }
    if (l16 == 0) {
        float z0 = a0 / sw + b2[0];
        float z1 = a1 / sw + b2[1];
        float mz = fmaxf(z0, z1);
        float lse = mz + logf(__expf(z0 - mz) + __expf(z1 - mz));
        out[wid * NCLS + 0] = z0 - lse;
        out[wid * NCLS + 1] = z1 - lse;
    }
}

// ---------------- launch ----------------

extern "C" void kernel_launch(void* const* d_in, const int* in_sizes, int n_in,
                              void* d_out, int out_size, void* d_ws, size_t ws_size,
                              hipStream_t stream) {
    const float* x   = (const float*)d_in[0];
    const int*   ei  = (const int*)d_in[1];
    const float* W1  = (const float*)d_in[2];
    const float* as1 = (const float*)d_in[3];
    const float* ad1 = (const float*)d_in[4];
    const float* b1  = (const float*)d_in[5];
    const float* W2  = (const float*)d_in[6];
    const float* as2 = (const float*)d_in[7];
    const float* ad2 = (const float*)d_in[8];
    const float* b2  = (const float*)d_in[9];
    float* out = (float*)d_out;

    const int n = in_sizes[0] / FIN;     // 50000
    const int e = in_sizes[1] / 2;       // 1600000
    const int tot = e + n;               // edges incl. self-loops

    char* ws = (char*)d_ws;
    size_t off = 0;
    auto alloc = [&](size_t bytes) -> void* {
        void* p = ws + off;
        off += (bytes + 255) & ~(size_t)255;
        return p;
    };
    __hip_bfloat16* h1b = (__hip_bfloat16*)alloc((size_t)n * HC * 2);
    int* pairs   = (int*)alloc((size_t)NBKT * CAP * 4);     // 8 MB, fixed slots
    int* csr     = (int*)alloc((size_t)NBKT * CAP * 4);     // 8 MB, padded layout
    float* es1   = (float*)alloc((size_t)n * NHEAD * 4);
    float* ed1   = (float*)alloc((size_t)n * NHEAD * 4);
    float4* node2 = (float4*)alloc((size_t)n * 16);
    int* rowptr  = (int*)alloc((size_t)n * 4);
    int* degv    = (int*)alloc((size_t)n * 4);
    int* bcur    = (int*)alloc(NBKT * 4);

    const int nbin = (tot + BCHUNK - 1) / BCHUNK;   // 403

    hipMemsetAsync(bcur, 0, NBKT * 4, stream);
    // fused: binning (403 blocks) || layer-1 GEMM (1024 blocks)
    k_bin_h1<<<nbin + 1024, 256, 0, stream>>>(ei, bcur, pairs, e, tot, nbin,
                                              x, W1, as1, ad1, h1b, es1, ed1, n);
    k_bucket_csr<<<NBKT, 256, 0, stream>>>(pairs, bcur, rowptr, degv, csr, n);
    k_agg1<<<(n * 64 + 255) / 256, 256, 0, stream>>>(h1b, es1, ed1, rowptr, degv, csr,
                                                     b1, W2, as2, ad2, node2, n);
    k_agg2<<<(n * 16 + 255) / 256, 256, 0, stream>>>(node2, rowptr, degv, csr, b2, out, n);
}

// Round 10
// 121.197 us; speedup vs baseline: 3.3893x; 1.0031x over previous
//
#include <hip/hip_runtime.h>
#include <hip/hip_bf16.h>
#include <math.h>

#define NN 50000
#define FIN 48
#define HC 64   // 8 heads x 8 ch
#define NHEAD 8
#define NCH 8
#define NCLS 2
#define NEG 0.2f
#define LOG2E 1.44269504f

#define NPB 98                         // nodes per bucket
#define NBKT 512                       // buckets (NPB*NBKT >= NN)
#define CAP 4096                       // fixed slot capacity (E[fill]=3225, +15 sigma)
#define BCHUNK 4096                    // edges per binning workgroup

// ---------------- fused: edge binning (blocks 0..nbin-1)  ||  layer-1 GEMM (rest) ----------------

__global__ void k_bin_h1(const int* __restrict__ ei, int* __restrict__ bcur,
                         int* __restrict__ pairs, int e, int tot, int nbin,
                         const float* __restrict__ x, const float* __restrict__ W1,
                         const float* __restrict__ as1, const float* __restrict__ ad1,
                         __hip_bfloat16* __restrict__ h1b, __hip_bfloat16* __restrict__ es1b,
                         float* __restrict__ ed1, int n) {
    __shared__ int hist[NBKT];
    __shared__ int gbase[NBKT];
    __shared__ float Wl[FIN * HC];
    __shared__ float xs[4][FIN];
    __shared__ float hr[4][HC];
    int t = threadIdx.x;
    if ((int)blockIdx.x < nbin) {
        // ---- binning: one-pass WG-local counting sort ----
        hist[t] = 0; hist[t + 256] = 0;
        __syncthreads();
        int base = blockIdx.x * BCHUNK;
        int end = min(base + BCHUNK, tot);
        int pk[16];   // payload (dloc<<16 | src)
        int bp[16];   // (bucket<<16 | local pos)
        #pragma unroll
        for (int k = 0; k < 16; ++k) {
            int i = base + t + k * 256;
            if (i < end) {
                int s, d;
                if (i < e) { s = ei[i]; d = ei[e + i]; }
                else       { s = d = i - e; }
                int b = d / NPB;
                int p = atomicAdd(&hist[b], 1);
                pk[k] = ((d - b * NPB) << 16) | s;
                bp[k] = (b << 16) | p;
            }
        }
        __syncthreads();
        for (int u = t; u < NBKT; u += 256) {
            int h = hist[u];
            gbase[u] = h ? atomicAdd(&bcur[u], h) : 0;
        }
        __syncthreads();
        #pragma unroll
        for (int k = 0; k < 16; ++k) {
            int i = base + t + k * 256;
            if (i < end) {
                int b = bp[k] >> 16;
                int p = gbase[b] + (bp[k] & 0xFFFF);
                if (p < CAP) pairs[b * CAP + p] = pk[k];
            }
        }
    } else {
        // ---- layer-1: h1 = x @ W1 (bf16) ; es (bf16) / ed (f32) pre-scaled by 1/ln2 ----
        for (int i = t; i < FIN * HC; i += 256) Wl[i] = W1[i];
        int ngroups = (n + 3) >> 2;
        int nl = t >> 6, j = t & 63;
        for (int g = blockIdx.x - nbin; g < ngroups; g += gridDim.x - nbin) {
            int nb = g * 4;
            __syncthreads();
            for (int i = t; i < 4 * FIN; i += 256) {
                int l = i / FIN, k = i % FIN;
                int nd = nb + l;
                xs[l][k] = (nd < n) ? x[nd * FIN + k] : 0.f;
            }
            __syncthreads();
            float acc = 0.f;
            #pragma unroll
            for (int k = 0; k < FIN; ++k) acc += xs[nl][k] * Wl[k * HC + j];
            int nd = nb + nl;
            if (nd < n) h1b[nd * HC + j] = __float2bfloat16(acc);
            hr[nl][j] = acc;
            __syncthreads();
            if (j < 16 && nd < n) {
                int hh = j & 7;
                const float* av = (j < 8) ? as1 : ad1;
                float ev = 0.f;
                #pragma unroll
                for (int c = 0; c < NCH; ++c) ev += hr[nl][hh * NCH + c] * av[hh * NCH + c];
                ev *= LOG2E;
                if (j < 8) es1b[nd * NHEAD + hh] = __float2bfloat16(ev);
                else       ed1[nd * NHEAD + hh] = ev;
            }
        }
    }
}

// ---------------- per-bucket CSR: one pass (register-stashed positions) ----------------

__global__ void k_bucket_csr(const int* __restrict__ pairs, const int* __restrict__ bcur,
                             int* __restrict__ rowptr, int* __restrict__ degv,
                             int* __restrict__ csr, int n) {
    __shared__ int hist[256];
    int b = blockIdx.x, t = threadIdx.x;
    int lo = b * NPB;
    int nn = min(NPB, n - lo);
    if (nn <= 0) return;
    int base = b * CAP;
    int cnt = min(bcur[b], CAP);
    hist[t] = 0;
    __syncthreads();
    int srcv[16];  // src id
    int kp[16];    // (key<<16 | pos)
    #pragma unroll
    for (int k = 0; k < 16; ++k) {
        int i = t + k * 256;
        if (i < cnt) {
            int p = pairs[base + i];
            int key = p >> 16;
            int pos = atomicAdd(&hist[key], 1);
            srcv[k] = p & 0xFFFF;
            kp[k] = (key << 16) | pos;
        }
    }
    __syncthreads();
    int v = hist[t];
    for (int off = 1; off < 256; off <<= 1) {           // inclusive scan
        int y = (t >= off) ? hist[t - off] : 0;
        __syncthreads();
        hist[t] += y;
        __syncthreads();
    }
    int excl = hist[t] - v;
    if (t < nn) { rowptr[lo + t] = base + excl; degv[lo + t] = v; }
    __syncthreads();
    hist[t] = excl;                                      // rewrite as exclusive offsets
    __syncthreads();
    #pragma unroll
    for (int k = 0; k < 16; ++k) {
        int i = t + k * 256;
        if (i < cnt) {
            int key = kp[k] >> 16, pos = kp[k] & 0xFFFF;
            csr[base + hist[key] + pos] = srcv[k];
        }
    }
}

// ---------------- Layer 1 aggregation + fused layer-2 linear ----------------
// wave per dst node; software-pipelined. Weight lane = j*8+hw so each edge's
// es1 row (16 B) is read by 8 CONSECUTIVE lanes (coalesced). Accum: 16 lanes
// x 4 channels per edge, uint2 (4 bf16) loads, consecutive lanes cover row.

__global__ void k_agg1(const __hip_bfloat16* __restrict__ h1b, const __hip_bfloat16* __restrict__ es1b,
                       const float* __restrict__ ed1, const int* __restrict__ rowptr,
                       const int* __restrict__ degv, const int* __restrict__ csr,
                       const float* __restrict__ b1,
                       const float* __restrict__ W2, const float* __restrict__ as2,
                       const float* __restrict__ ad2, float4* __restrict__ node2, int n) {
    int wid = (blockIdx.x * blockDim.x + threadIdx.x) >> 6;
    if (wid >= n) return;
    int lane = threadIdx.x & 63;
    int j  = lane >> 3;                      // weight: edge slot (0..7)
    int hw = lane & 7;                       // weight: head
    int e4 = lane >> 4;                      // accum: edge sub-slot (0..3)
    int r  = lane & 15;
    int ha = r >> 1;                         // accum: head
    int ch0 = (ha << 3) + ((r & 1) << 2);    // first of this lane's 4 channels
    int wbase = (e4 << 3) + ha;              // lane with w(edge e4, head ha); +32 -> edge e4+4
    int start = rowptr[wid];
    int cnt = degv[wid];
    float edv = ed1[wid * NHEAD + hw];
    float sumw = 0.f;
    float a0 = 0.f, a1 = 0.f, a2 = 0.f, a3 = 0.f;
    int nbatch = cnt >> 3;

    int sl; float ev; uint2 va, vb;
    if (nbatch > 0) {
        sl = __builtin_nontemporal_load(csr + start + j);
        ev = __bfloat162float(es1b[sl * NHEAD + hw]);
        int su0 = __shfl(sl, e4 << 3, 64);
        int su1 = __shfl(sl, (4 + e4) << 3, 64);
        va = *(const uint2*)(h1b + su0 * HC + ch0);
        vb = *(const uint2*)(h1b + su1 * HC + ch0);
        for (int b = 1; b < nbatch; ++b) {
            int sl_n = __builtin_nontemporal_load(csr + start + b * 8 + j);
            float ev_n = __bfloat162float(es1b[sl_n * NHEAD + hw]);
            int su0n = __shfl(sl_n, e4 << 3, 64);
            int su1n = __shfl(sl_n, (4 + e4) << 3, 64);
            uint2 va_n = *(const uint2*)(h1b + su0n * HC + ch0);
            uint2 vb_n = *(const uint2*)(h1b + su1n * HC + ch0);
            float tt = ev + edv;
            tt = fmaxf(tt, NEG * tt);
            float w = exp2f(tt);
            sumw += w;
            float wj0 = __shfl(w, wbase, 64);
            float wj1 = __shfl(w, wbase + 32, 64);
            a0 += wj0 * __uint_as_float(va.x << 16);
            a1 += wj0 * __uint_as_float(va.x & 0xffff0000u);
            a2 += wj0 * __uint_as_float(va.y << 16);
            a3 += wj0 * __uint_as_float(va.y & 0xffff0000u);
            a0 += wj1 * __uint_as_float(vb.x << 16);
            a1 += wj1 * __uint_as_float(vb.x & 0xffff0000u);
            a2 += wj1 * __uint_as_float(vb.y << 16);
            a3 += wj1 * __uint_as_float(vb.y & 0xffff0000u);
            sl = sl_n; ev = ev_n; va = va_n; vb = vb_n;
        }
        float tt = ev + edv;
        tt = fmaxf(tt, NEG * tt);
        float w = exp2f(tt);
        sumw += w;
        float wj0 = __shfl(w, wbase, 64);
        float wj1 = __shfl(w, wbase + 32, 64);
        a0 += wj0 * __uint_as_float(va.x << 16);
        a1 += wj0 * __uint_as_float(va.x & 0xffff0000u);
        a2 += wj0 * __uint_as_float(va.y << 16);
        a3 += wj0 * __uint_as_float(va.y & 0xffff0000u);
        a0 += wj1 * __uint_as_float(vb.x << 16);
        a1 += wj1 * __uint_as_float(vb.x & 0xffff0000u);
        a2 += wj1 * __uint_as_float(vb.y << 16);
        a3 += wj1 * __uint_as_float(vb.y & 0xffff0000u);
    }
    int i = nbatch << 3;
    if (i < cnt) {                            // tail batch (peeled, clamped)
        int last = start + cnt - 1;
        int idx = start + i + j;
        int slt = csr[idx > last ? last : idx];
        float evt = __bfloat162float(es1b[slt * NHEAD + hw]) + edv;
        evt = fmaxf(evt, NEG * evt);
        float w = (i + j < cnt) ? exp2f(evt) : 0.f;
        sumw += w;
        #pragma unroll
        for (int it = 0; it < 2; ++it) {
            int su   = __shfl(slt, ((it << 2) + e4) << 3, 64);
            float wj = __shfl(w, wbase + (it << 5), 64);
            uint2 v = *(const uint2*)(h1b + su * HC + ch0);
            a0 += wj * __uint_as_float(v.x << 16);
            a1 += wj * __uint_as_float(v.x & 0xffff0000u);
            a2 += wj * __uint_as_float(v.y << 16);
            a3 += wj * __uint_as_float(v.y & 0xffff0000u);
        }
    }
    // denominator: sum over edge slots j (lane stride 8) for fixed head hw
    sumw += __shfl_xor(sumw, 8, 64);
    sumw += __shfl_xor(sumw, 16, 64);
    sumw += __shfl_xor(sumw, 32, 64);
    // accumulator: sum the 4 edge sub-groups (lanes with same r)
    a0 += __shfl_xor(a0, 16, 64); a0 += __shfl_xor(a0, 32, 64);
    a1 += __shfl_xor(a1, 16, 64); a1 += __shfl_xor(a1, 32, 64);
    a2 += __shfl_xor(a2, 16, 64); a2 += __shfl_xor(a2, 32, 64);
    a3 += __shfl_xor(a3, 16, 64); a3 += __shfl_xor(a3, 32, 64);
    float sden = __shfl(sumw, ha, 64);        // lane ha holds (j=0, hw=ha)
    float4 bv = *(const float4*)(b1 + ch0);
    float o0 = a0 / sden + bv.x;
    float o1 = a1 / sden + bv.y;
    float o2 = a2 / sden + bv.z;
    float o3 = a3 / sden + bv.w;
    o0 = o0 > 0.f ? o0 : expm1f(o0);          // fused bias + ELU
    o1 = o1 > 0.f ? o1 : expm1f(o1);
    o2 = o2 > 0.f ? o2 : expm1f(o2);
    o3 = o3 > 0.f ? o3 : expm1f(o3);
    float4 w01 = *(const float4*)(W2 + ch0 * 2);
    float4 w23 = *(const float4*)(W2 + ch0 * 2 + 4);
    float p0 = o0 * w01.x + o1 * w01.z + o2 * w23.x + o3 * w23.z;
    float p1 = o0 * w01.y + o1 * w01.w + o2 * w23.y + o3 * w23.w;
    #pragma unroll
    for (int off = 8; off > 0; off >>= 1) {
        p0 += __shfl_xor(p0, off, 64);
        p1 += __shfl_xor(p1, off, 64);
    }
    if (lane == 0) {
        float es2v = (p0 * as2[0] + p1 * as2[1]) * LOG2E;
        float ed2v = (p0 * ad2[0] + p1 * ad2[1]) * LOG2E;
        node2[wid] = make_float4(es2v, p0, p1, ed2v);
    }
}

// ---------------- Layer 2 aggregation + bias + log_softmax ----------------

__global__ void k_agg2(const float4* __restrict__ node2, const int* __restrict__ rowptr,
                       const int* __restrict__ degv, const int* __restrict__ csr,
                       const float* __restrict__ b2, float* __restrict__ out, int n) {
    int lane = threadIdx.x & 63;
    int wid = ((blockIdx.x * blockDim.x + threadIdx.x) >> 6) * 4 + (lane >> 4);
    if (wid >= n) return;
    int l16 = lane & 15;
    int start = rowptr[wid];
    int cnt = degv[wid];
    float edv = ((const float*)node2)[wid * 4 + 3];
    float sw = 0.f, a0 = 0.f, a1 = 0.f;
    for (int i = l16; i < cnt; i += 16) {
        int s = __builtin_nontemporal_load(csr + start + i);
        float4 t = node2[s];
        float val = t.x + edv;
        val = fmaxf(val, NEG * val);
        float w = exp2f(val);
        sw += w;
        a0 += w * t.y;
        a1 += w * t.z;
    }
    #pragma unroll
    for (int off = 8; off > 0; off >>= 1) {
        sw += __shfl_xor(sw, off, 16);
        a0 += __shfl_xor(a0, off, 16);
        a1 += __shfl_xor(a1, off, 16);
    }
    if (l16 == 0) {
        float z0 = a0 / sw + b2[0];
        float z1 = a1 / sw + b2[1];
        float mz = fmaxf(z0, z1);
        float lse = mz + logf(__expf(z0 - mz) + __expf(z1 - mz));
        out[wid * NCLS + 0] = z0 - lse;
        out[wid * NCLS + 1] = z1 - lse;
    }
}

// ---------------- launch ----------------

extern "C" void kernel_launch(void* const* d_in, const int* in_sizes, int n_in,
                              void* d_out, int out_size, void* d_ws, size_t ws_size,
                              hipStream_t stream) {
    const float* x   = (const float*)d_in[0];
    const int*   ei  = (const int*)d_in[1];
    const float* W1  = (const float*)d_in[2];
    const float* as1 = (const float*)d_in[3];
    const float* ad1 = (const float*)d_in[4];
    const float* b1  = (const float*)d_in[5];
    const float* W2  = (const float*)d_in[6];
    const float* as2 = (const float*)d_in[7];
    const float* ad2 = (const float*)d_in[8];
    const float* b2  = (const float*)d_in[9];
    float* out = (float*)d_out;

    const int n = in_sizes[0] / FIN;     // 50000
    const int e = in_sizes[1] / 2;       // 1600000
    const int tot = e + n;               // edges incl. self-loops

    char* ws = (char*)d_ws;
    size_t off = 0;
    auto alloc = [&](size_t bytes) -> void* {
        void* p = ws + off;
        off += (bytes + 255) & ~(size_t)255;
        return p;
    };
    __hip_bfloat16* h1b  = (__hip_bfloat16*)alloc((size_t)n * HC * 2);
    __hip_bfloat16* es1b = (__hip_bfloat16*)alloc((size_t)n * NHEAD * 2);
    int* pairs   = (int*)alloc((size_t)NBKT * CAP * 4);     // 8 MB, fixed slots
    int* csr     = (int*)alloc((size_t)NBKT * CAP * 4);     // 8 MB, padded layout
    float* ed1   = (float*)alloc((size_t)n * NHEAD * 4);
    float4* node2 = (float4*)alloc((size_t)n * 16);
    int* rowptr  = (int*)alloc((size_t)n * 4);
    int* degv    = (int*)alloc((size_t)n * 4);
    int* bcur    = (int*)alloc(NBKT * 4);

    const int nbin = (tot + BCHUNK - 1) / BCHUNK;   // 403

    hipMemsetAsync(bcur, 0, NBKT * 4, stream);
    // fused: binning (403 blocks) || layer-1 GEMM (1024 blocks)
    k_bin_h1<<<nbin + 1024, 256, 0, stream>>>(ei, bcur, pairs, e, tot, nbin,
                                              x, W1, as1, ad1, h1b, es1b, ed1, n);
    k_bucket_csr<<<NBKT, 256, 0, stream>>>(pairs, bcur, rowptr, degv, csr, n);
    k_agg1<<<(n * 64 + 255) / 256, 256, 0, stream>>>(h1b, es1b, ed1, rowptr, degv, csr,
                                                     b1, W2, as2, ad2, node2, n);
    k_agg2<<<(n * 16 + 255) / 256, 256, 0, stream>>>(node2, rowptr, degv, csr, b2, out, n);
}

// Round 11
// 110.981 us; speedup vs baseline: 3.7012x; 1.0920x over previous
//
#include <hip/hip_runtime.h>
#include <hip/hip_bf16.h>
#include <math.h>

#define NN 50000
#define FIN 48
#define HC 64   // 8 heads x 8 ch
#define NHEAD 8
#define NCH 8
#define NCLS 2
#define NEG 0.2f
#define LOG2E 1.44269504f

#define NPB 98                         // nodes per bucket
#define NBKT 512                       // buckets (NPB*NBKT >= NN)
#define CAP 4096                       // fixed slot capacity (E[fill]=3225, +15 sigma)
#define BCHUNK 4096                    // edges per binning workgroup

// ---------------- fused: edge binning (blocks 0..nbin-1)  ||  layer-1 GEMM (rest) ----------------

__global__ void k_bin_h1(const int* __restrict__ ei, int* __restrict__ bcur,
                         int* __restrict__ pairs, int e, int tot, int nbin,
                         const float* __restrict__ x, const float* __restrict__ W1,
                         const float* __restrict__ as1, const float* __restrict__ ad1,
                         __hip_bfloat16* __restrict__ h1b, __hip_bfloat16* __restrict__ es1b,
                         float* __restrict__ ed1, int n) {
    __shared__ int hist[NBKT];
    __shared__ int gbase[NBKT];
    __shared__ float Wl[FIN * HC];
    __shared__ float xs[4][FIN];
    __shared__ float hr[4][HC];
    int t = threadIdx.x;
    if ((int)blockIdx.x < nbin) {
        // ---- binning: one-pass WG-local counting sort ----
        hist[t] = 0; hist[t + 256] = 0;
        __syncthreads();
        int base = blockIdx.x * BCHUNK;
        int end = min(base + BCHUNK, tot);
        int pk[16];   // payload (dloc<<16 | src)
        int bp[16];   // (bucket<<16 | local pos)
        #pragma unroll
        for (int k = 0; k < 16; ++k) {
            int i = base + t + k * 256;
            if (i < end) {
                int s, d;
                if (i < e) { s = ei[i]; d = ei[e + i]; }
                else       { s = d = i - e; }
                int b = d / NPB;
                int p = atomicAdd(&hist[b], 1);
                pk[k] = ((d - b * NPB) << 16) | s;
                bp[k] = (b << 16) | p;
            }
        }
        __syncthreads();
        for (int u = t; u < NBKT; u += 256) {
            int h = hist[u];
            gbase[u] = h ? atomicAdd(&bcur[u], h) : 0;
        }
        __syncthreads();
        #pragma unroll
        for (int k = 0; k < 16; ++k) {
            int i = base + t + k * 256;
            if (i < end) {
                int b = bp[k] >> 16;
                int p = gbase[b] + (bp[k] & 0xFFFF);
                if (p < CAP) pairs[b * CAP + p] = pk[k];
            }
        }
    } else {
        // ---- layer-1: h1 = x @ W1 (bf16) ; es (bf16) / ed (f32) pre-scaled by 1/ln2 ----
        for (int i = t; i < FIN * HC; i += 256) Wl[i] = W1[i];
        int ngroups = (n + 3) >> 2;
        int nl = t >> 6, j = t & 63;
        for (int g = blockIdx.x - nbin; g < ngroups; g += gridDim.x - nbin) {
            int nb = g * 4;
            __syncthreads();
            for (int i = t; i < 4 * FIN; i += 256) {
                int l = i / FIN, k = i % FIN;
                int nd = nb + l;
                xs[l][k] = (nd < n) ? x[nd * FIN + k] : 0.f;
            }
            __syncthreads();
            float acc = 0.f;
            #pragma unroll
            for (int k = 0; k < FIN; ++k) acc += xs[nl][k] * Wl[k * HC + j];
            int nd = nb + nl;
            if (nd < n) h1b[nd * HC + j] = __float2bfloat16(acc);
            hr[nl][j] = acc;
            __syncthreads();
            if (j < 16 && nd < n) {
                int hh = j & 7;
                const float* av = (j < 8) ? as1 : ad1;
                float ev = 0.f;
                #pragma unroll
                for (int c = 0; c < NCH; ++c) ev += hr[nl][hh * NCH + c] * av[hh * NCH + c];
                ev *= LOG2E;
                if (j < 8) es1b[nd * NHEAD + hh] = __float2bfloat16(ev);
                else       ed1[nd * NHEAD + hh] = ev;
            }
        }
    }
}

// ---------------- per-bucket CSR: one pass (register-stashed positions) ----------------

__global__ void k_bucket_csr(const int* __restrict__ pairs, const int* __restrict__ bcur,
                             int* __restrict__ rowptr, int* __restrict__ degv,
                             int* __restrict__ csr, int n) {
    __shared__ int hist[256];
    int b = blockIdx.x, t = threadIdx.x;
    int lo = b * NPB;
    int nn = min(NPB, n - lo);
    if (nn <= 0) return;
    int base = b * CAP;
    int cnt = min(bcur[b], CAP);
    hist[t] = 0;
    __syncthreads();
    int srcv[16];  // src id
    int kp[16];    // (key<<16 | pos)
    #pragma unroll
    for (int k = 0; k < 16; ++k) {
        int i = t + k * 256;
        if (i < cnt) {
            int p = pairs[base + i];
            int key = p >> 16;
            int pos = atomicAdd(&hist[key], 1);
            srcv[k] = p & 0xFFFF;
            kp[k] = (key << 16) | pos;
        }
    }
    __syncthreads();
    int v = hist[t];
    for (int off = 1; off < 256; off <<= 1) {           // inclusive scan
        int y = (t >= off) ? hist[t - off] : 0;
        __syncthreads();
        hist[t] += y;
        __syncthreads();
    }
    int excl = hist[t] - v;
    if (t < nn) { rowptr[lo + t] = base + excl; degv[lo + t] = v; }
    __syncthreads();
    hist[t] = excl;                                      // rewrite as exclusive offsets
    __syncthreads();
    #pragma unroll
    for (int k = 0; k < 16; ++k) {
        int i = t + k * 256;
        if (i < cnt) {
            int key = kp[k] >> 16, pos = kp[k] & 0xFFFF;
            csr[base + hist[key] + pos] = srcv[k];
        }
    }
}

// ---------------- Layer 1 aggregation + fused layer-2 linear ----------------
// wave per dst node. KEY: the whole csr row (<=64 entries) is preloaded into
// one register per lane (rv); batch src ids come from __shfl(rv,..) — no
// load->address dependency inside the loop, so all gathers pipeline freely.

__global__ void k_agg1(const __hip_bfloat16* __restrict__ h1b, const __hip_bfloat16* __restrict__ es1b,
                       const float* __restrict__ ed1, const int* __restrict__ rowptr,
                       const int* __restrict__ degv, const int* __restrict__ csr,
                       const float* __restrict__ b1,
                       const float* __restrict__ W2, const float* __restrict__ as2,
                       const float* __restrict__ ad2, float4* __restrict__ node2, int n) {
    int wid = (blockIdx.x * blockDim.x + threadIdx.x) >> 6;
    if (wid >= n) return;
    int lane = threadIdx.x & 63;
    int j  = lane >> 3;                      // weight: edge slot (0..7)
    int hw = lane & 7;                       // weight: head
    int e4 = lane >> 4;                      // accum: edge sub-slot (0..3)
    int r  = lane & 15;
    int ha = r >> 1;                         // accum: head
    int ch0 = (ha << 3) + ((r & 1) << 2);    // first of this lane's 4 channels
    int wbase = (e4 << 3) + ha;              // lane with w(edge e4, head ha); +32 -> edge e4+4
    int start = rowptr[wid];
    int cnt = degv[wid];
    float edv = ed1[wid * NHEAD + hw];
    float sumw = 0.f;
    float a0 = 0.f, a1 = 0.f, a2 = 0.f, a3 = 0.f;
    int nbatch = cnt >> 3;

    // preload first 64 src ids of the row (cnt >= 1 always: self-loop)
    int rv = csr[start + min(lane, cnt - 1)];

    int sl; float ev; uint2 va, vb;
    if (nbatch > 0) {
        sl = __shfl(rv, j, 64);
        ev = __bfloat162float(es1b[sl * NHEAD + hw]);
        int su0 = __shfl(sl, e4 << 3, 64);
        int su1 = __shfl(sl, (4 + e4) << 3, 64);
        va = *(const uint2*)(h1b + su0 * HC + ch0);
        vb = *(const uint2*)(h1b + su1 * HC + ch0);
        for (int b = 1; b < nbatch; ++b) {
            int sl_n;
            if (b < 8) sl_n = __shfl(rv, (b << 3) + j, 64);   // register-sourced
            else       sl_n = csr[start + (b << 3) + j];      // deg>64: rare fallback
            float ev_n = __bfloat162float(es1b[sl_n * NHEAD + hw]);
            int su0n = __shfl(sl_n, e4 << 3, 64);
            int su1n = __shfl(sl_n, (4 + e4) << 3, 64);
            uint2 va_n = *(const uint2*)(h1b + su0n * HC + ch0);
            uint2 vb_n = *(const uint2*)(h1b + su1n * HC + ch0);
            // consume previous batch
            float tt = ev + edv;
            tt = fmaxf(tt, NEG * tt);
            float w = exp2f(tt);
            sumw += w;
            float wj0 = __shfl(w, wbase, 64);
            float wj1 = __shfl(w, wbase + 32, 64);
            a0 += wj0 * __uint_as_float(va.x << 16);
            a1 += wj0 * __uint_as_float(va.x & 0xffff0000u);
            a2 += wj0 * __uint_as_float(va.y << 16);
            a3 += wj0 * __uint_as_float(va.y & 0xffff0000u);
            a0 += wj1 * __uint_as_float(vb.x << 16);
            a1 += wj1 * __uint_as_float(vb.x & 0xffff0000u);
            a2 += wj1 * __uint_as_float(vb.y << 16);
            a3 += wj1 * __uint_as_float(vb.y & 0xffff0000u);
            sl = sl_n; ev = ev_n; va = va_n; vb = vb_n;
        }
        float tt = ev + edv;
        tt = fmaxf(tt, NEG * tt);
        float w = exp2f(tt);
        sumw += w;
        float wj0 = __shfl(w, wbase, 64);
        float wj1 = __shfl(w, wbase + 32, 64);
        a0 += wj0 * __uint_as_float(va.x << 16);
        a1 += wj0 * __uint_as_float(va.x & 0xffff0000u);
        a2 += wj0 * __uint_as_float(va.y << 16);
        a3 += wj0 * __uint_as_float(va.y & 0xffff0000u);
        a0 += wj1 * __uint_as_float(vb.x << 16);
        a1 += wj1 * __uint_as_float(vb.x & 0xffff0000u);
        a2 += wj1 * __uint_as_float(vb.y << 16);
        a3 += wj1 * __uint_as_float(vb.y & 0xffff0000u);
    }
    int i = nbatch << 3;
    if (i < cnt) {                            // tail batch (clamped)
        int idx = min(i + j, cnt - 1);
        int slt = (cnt <= 64) ? __shfl(rv, idx, 64) : csr[start + idx];
        float evt = __bfloat162float(es1b[slt * NHEAD + hw]) + edv;
        evt = fmaxf(evt, NEG * evt);
        float w = (i + j < cnt) ? exp2f(evt) : 0.f;
        sumw += w;
        #pragma unroll
        for (int it = 0; it < 2; ++it) {
            int su   = __shfl(slt, ((it << 2) + e4) << 3, 64);
            float wj = __shfl(w, wbase + (it << 5), 64);
            uint2 v = *(const uint2*)(h1b + su * HC + ch0);
            a0 += wj * __uint_as_float(v.x << 16);
            a1 += wj * __uint_as_float(v.x & 0xffff0000u);
            a2 += wj * __uint_as_float(v.y << 16);
            a3 += wj * __uint_as_float(v.y & 0xffff0000u);
        }
    }
    // denominator: sum over edge slots j (lane stride 8) for fixed head hw
    sumw += __shfl_xor(sumw, 8, 64);
    sumw += __shfl_xor(sumw, 16, 64);
    sumw += __shfl_xor(sumw, 32, 64);
    // accumulator: sum the 4 edge sub-groups (lanes with same r)
    a0 += __shfl_xor(a0, 16, 64); a0 += __shfl_xor(a0, 32, 64);
    a1 += __shfl_xor(a1, 16, 64); a1 += __shfl_xor(a1, 32, 64);
    a2 += __shfl_xor(a2, 16, 64); a2 += __shfl_xor(a2, 32, 64);
    a3 += __shfl_xor(a3, 16, 64); a3 += __shfl_xor(a3, 32, 64);
    float sden = __shfl(sumw, ha, 64);        // lane ha holds (j=0, hw=ha)
    float4 bv = *(const float4*)(b1 + ch0);
    float o0 = a0 / sden + bv.x;
    float o1 = a1 / sden + bv.y;
    float o2 = a2 / sden + bv.z;
    float o3 = a3 / sden + bv.w;
    o0 = o0 > 0.f ? o0 : expm1f(o0);          // fused bias + ELU
    o1 = o1 > 0.f ? o1 : expm1f(o1);
    o2 = o2 > 0.f ? o2 : expm1f(o2);
    o3 = o3 > 0.f ? o3 : expm1f(o3);
    float4 w01 = *(const float4*)(W2 + ch0 * 2);
    float4 w23 = *(const float4*)(W2 + ch0 * 2 + 4);
    float p0 = o0 * w01.x + o1 * w01.z + o2 * w23.x + o3 * w23.z;
    float p1 = o0 * w01.y + o1 * w01.w + o2 * w23.y + o3 * w23.w;
    #pragma unroll
    for (int off = 8; off > 0; off >>= 1) {
        p0 += __shfl_xor(p0, off, 64);
        p1 += __shfl_xor(p1, off, 64);
    }
    if (lane == 0) {
        float es2v = (p0 * as2[0] + p1 * as2[1]) * LOG2E;
        float ed2v = (p0 * ad2[0] + p1 * ad2[1]) * LOG2E;
        node2[wid] = make_float4(es2v, p0, p1, ed2v);
    }
}

// ---------------- Layer 2 aggregation + bias + log_softmax ----------------
// 16-lane segment per node; csr row preloaded into registers the same way.

__global__ void k_agg2(const float4* __restrict__ node2, const int* __restrict__ rowptr,
                       const int* __restrict__ degv, const int* __restrict__ csr,
                       const float* __restrict__ b2, float* __restrict__ out, int n) {
    int lane = threadIdx.x & 63;
    int wid = ((blockIdx.x * blockDim.x + threadIdx.x) >> 6) * 4 + (lane >> 4);
    if (wid >= n) return;
    int l16 = lane & 15;
    int start = rowptr[wid];
    int cnt = degv[wid];
    float edv = ((const float*)node2)[wid * 4 + 3];
    float sw = 0.f, a0 = 0.f, a1 = 0.f;
    for (int i = l16; i < cnt; i += 16) {
        int s = __builtin_nontemporal_load(csr + start + i);
        float4 t = node2[s];
        float val = t.x + edv;
        val = fmaxf(val, NEG * val);
        float w = exp2f(val);
        sw += w;
        a0 += w * t.y;
        a1 += w * t.z;
    }
    #pragma unroll
    for (int off = 8; off > 0; off >>= 1) {
        sw += __shfl_xor(sw, off, 16);
        a0 += __shfl_xor(a0, off, 16);
        a1 += __shfl_xor(a1, off, 16);
    }
    if (l16 == 0) {
        float z0 = a0 / sw + b2[0];
        float z1 = a1 / sw + b2[1];
        float mz = fmaxf(z0, z1);
        float lse = mz + logf(__expf(z0 - mz) + __expf(z1 - mz));
        out[wid * NCLS + 0] = z0 - lse;
        out[wid * NCLS + 1] = z1 - lse;
    }
}

// ---------------- launch ----------------

extern "C" void kernel_launch(void* const* d_in, const int* in_sizes, int n_in,
                              void* d_out, int out_size, void* d_ws, size_t ws_size,
                              hipStream_t stream) {
    const float* x   = (const float*)d_in[0];
    const int*   ei  = (const int*)d_in[1];
    const float* W1  = (const float*)d_in[2];
    const float* as1 = (const float*)d_in[3];
    const float* ad1 = (const float*)d_in[4];
    const float* b1  = (const float*)d_in[5];
    const float* W2  = (const float*)d_in[6];
    const float* as2 = (const float*)d_in[7];
    const float* ad2 = (const float*)d_in[8];
    const float* b2  = (const float*)d_in[9];
    float* out = (float*)d_out;

    const int n = in_sizes[0] / FIN;     // 50000
    const int e = in_sizes[1] / 2;       // 1600000
    const int tot = e + n;               // edges incl. self-loops

    char* ws = (char*)d_ws;
    size_t off = 0;
    auto alloc = [&](size_t bytes) -> void* {
        void* p = ws + off;
        off += (bytes + 255) & ~(size_t)255;
        return p;
    };
    __hip_bfloat16* h1b  = (__hip_bfloat16*)alloc((size_t)n * HC * 2);
    __hip_bfloat16* es1b = (__hip_bfloat16*)alloc((size_t)n * NHEAD * 2);
    int* pairs   = (int*)alloc((size_t)NBKT * CAP * 4);     // 8 MB, fixed slots
    int* csr     = (int*)alloc((size_t)NBKT * CAP * 4);     // 8 MB, padded layout
    float* ed1   = (float*)alloc((size_t)n * NHEAD * 4);
    float4* node2 = (float4*)alloc((size_t)n * 16);
    int* rowptr  = (int*)alloc((size_t)n * 4);
    int* degv    = (int*)alloc((size_t)n * 4);
    int* bcur    = (int*)alloc(NBKT * 4);

    const int nbin = (tot + BCHUNK - 1) / BCHUNK;   // 403

    hipMemsetAsync(bcur, 0, NBKT * 4, stream);
    // fused: binning (403 blocks) || layer-1 GEMM (1024 blocks)
    k_bin_h1<<<nbin + 1024, 256, 0, stream>>>(ei, bcur, pairs, e, tot, nbin,
                                              x, W1, as1, ad1, h1b, es1b, ed1, n);
    k_bucket_csr<<<NBKT, 256, 0, stream>>>(pairs, bcur, rowptr, degv, csr, n);
    k_agg1<<<(n * 64 + 255) / 256, 256, 0, stream>>>(h1b, es1b, ed1, rowptr, degv, csr,
                                                     b1, W2, as2, ad2, node2, n);
    k_agg2<<<(n * 16 + 255) / 256, 256, 0, stream>>>(node2, rowptr, degv, csr, b2, out, n);
}